// Round 8
// baseline (83.152 us; speedup 1.0000x reference)
//
#include <hip/hip_runtime.h>
#include <math.h>

#define LNUM 6
#define BNUM 8
#define NNUM 300
#define CNUM 20
#define HW   784
#define HW4  196   // HW/4
#define GH   448
#define NW   16    // mask words per (b,n): permuted bit order (popcount-invariant)
#define AW   5     // adjacency row words (300 bits -> 5 x u64)
#define RT   16    // bce rows per tile
#define NTILE 28   // 448/16 tiles per (b,c)
#define TOTBC  (BNUM*CNUM)          // 160

typedef unsigned long long ull;

// ---- device scratch (every consumed entry rewritten each launch; counters/acc self-reset) ----
__device__ float g_rm [BNUM*NNUM*HW];
__device__ ull   g_T  [BNUM*NNUM*NW];
__device__ int   g_s  [BNUM*NNUM];
__device__ ull   g_adj[BNUM*NNUM*AW];
// one 128-B cacheline per bc -> no cross-bc atomic serialization
struct PadD { double v; double pad[15]; };
__device__ PadD g_accbc[TOTBC];   // f64 partial per bc; exchanged to 0 by final block
__device__ int  g_bdone = 0;      // block-done root line; reset by final block

// One block per (b,n): mean over L (float4), relu, max-normalize, rm + bitmask + popcount.
__global__ void k_rm(const float* __restrict__ sm) {
    int bn  = blockIdx.x;
    int tid = threadIdx.x;               // 256
    int lane = tid & 63, wid = tid >> 6;
    __shared__ float wmax[4];
    __shared__ int   scount;
    if (tid == 0) scount = 0;
    const size_t lstr4 = (size_t)BNUM * NNUM * HW4;
    const float4* base = (const float4*)sm + (size_t)bn * HW4;
    bool act = tid < HW4;
    float4 v = {0.f, 0.f, 0.f, 0.f};
    if (act) {
        float4 a = {0.f, 0.f, 0.f, 0.f};
        #pragma unroll
        for (int l = 0; l < LNUM; ++l) {
            float4 x = base[(size_t)l * lstr4 + tid];
            a.x += x.x; a.y += x.y; a.z += x.z; a.w += x.w;
        }
        v.x = fmaxf(__fdiv_rn(a.x, 6.0f), 0.0f);
        v.y = fmaxf(__fdiv_rn(a.y, 6.0f), 0.0f);
        v.z = fmaxf(__fdiv_rn(a.z, 6.0f), 0.0f);
        v.w = fmaxf(__fdiv_rn(a.w, 6.0f), 0.0f);
    }
    float lm = fmaxf(fmaxf(v.x, v.y), fmaxf(v.z, v.w));
    #pragma unroll
    for (int off = 32; off; off >>= 1) lm = fmaxf(lm, __shfl_xor(lm, off));
    if (lane == 0) wmax[wid] = lm;
    __syncthreads();
    float mx = fmaxf(fmaxf(wmax[0], wmax[1]), fmaxf(wmax[2], wmax[3]));
    float d = mx + 1e-6f;
    float4 nv;
    nv.x = __fdiv_rn(v.x, d); nv.y = __fdiv_rn(v.y, d);
    nv.z = __fdiv_rn(v.z, d); nv.w = __fdiv_rn(v.w, d);
    if (act) ((float4*)g_rm)[(size_t)bn * HW4 + tid] = nv;
    float c[4] = {nv.x, nv.y, nv.z, nv.w};
    #pragma unroll
    for (int k = 0; k < 4; ++k) {
        bool pr = act && (c[k] > 0.7f);
        ull ball = __ballot(pr);
        if (lane == 0) {
            g_T[(size_t)bn * NW + k * 4 + wid] = ball;
            atomicAdd(&scount, __popcll(ball));
        }
    }
    __syncthreads();
    if (tid == 0) g_s[bn] = scount;
}

// One block per (b,i): adjacency row i via popcount(AND) + exact f32 (iou+dice)/2 > 0.5
__global__ void k_adj() {
    int blk = blockIdx.x;                // b*300 + i
    int b = blk / NNUM;
    int tid = threadIdx.x;               // 320 (5 waves)
    __shared__ ull Ti[NW];
    __shared__ int si_sh;
    if (tid < NW)  Ti[tid] = g_T[(size_t)blk * NW + tid];
    if (tid == NW) si_sh = g_s[blk];
    __syncthreads();
    bool a = false;
    int j = tid;
    if (j < NNUM) {
        const ull* Tj = &g_T[((size_t)b * NNUM + j) * NW];
        int inter = 0;
        #pragma unroll
        for (int w = 0; w < NW; ++w) inter += __popcll(Ti[w] & Tj[w]);
        int si = si_sh, sj = g_s[b * NNUM + j];
        int uni = si + sj - inter, tot = si + sj;
        float iou  = (uni == 0) ? 1.0f : __fdiv_rn((float)inter, (float)uni);
        float dice = (tot == 0) ? 1.0f : __fdiv_rn(2.0f * (float)inter, (float)tot);
        a = (0.5f * (iou + dice)) > 0.5f;
    }
    ull ball = __ballot(a);
    if ((tid & 63) == 0) g_adj[(size_t)blk * AW + (tid >> 6)] = ball;
}

// One block per (b,c), 896 threads (14 waves): parallel cluster (waves 0-4) +
// LDS meanmap + all 28 BCE tiles (2 per iteration) + spread fenceless finalization.
__global__ void __launch_bounds__(896, 1)
k_cmbce(const float* __restrict__ score, const int* __restrict__ label,
        const int* __restrict__ gt, float* __restrict__ out) {
    int bc = blockIdx.x;                 // b*C + c
    int b = bc / CNUM, c = bc - b * CNUM;
    int tid = threadIdx.x;               // 896
    int lane = tid & 63, wid = tid >> 6;
    bool active = (label[bc] != 0);      // block-uniform

    __shared__ ull adj_sh[NNUM][AW];
    __shared__ ull cand[AW], fin[AW], nwv[AW];
    __shared__ float wbv[AW], wbva[AW];
    __shared__ int   wbi[AW], wbia[AW];
    __shared__ int sh_has, sh_go, sh_last, sh_sa;
    __shared__ float sh_cf;
    __shared__ float m[HW];
    __shared__ float rowY[2 * RT * 28];  // two tiles per iteration
    __shared__ double wsum[14];

    if (active) {
        for (int idx = tid; idx < NNUM * AW; idx += 896)
            ((ull*)adj_sh)[idx] = g_adj[(size_t)b * NNUM * AW + idx];
        // ---- cand bits + per-wave argmaxes on waves 0..4 (j = tid) ----
        int j = tid;
        bool cb = false;
        if (wid < AW) {
            float sc = -INFINITY;
            if (j < NNUM) {
                sc = score[((size_t)b * NNUM + j) * CNUM + c];
                cb = sc > 0.01f;
            }
            ull ball = __ballot(cb);
            if (lane == 0) cand[wid] = ball;
            float bv  = cb ? sc : -INFINITY;          int bi  = cb ? j : NNUM;
            float bva = (j < NNUM) ? sc : -INFINITY;  int bia = (j < NNUM) ? j : NNUM;
            #pragma unroll
            for (int off = 1; off < 64; off <<= 1) {
                float ov = __shfl_xor(bv, off);  int oi = __shfl_xor(bi, off);
                if (ov > bv || (ov == bv && oi < bi)) { bv = ov; bi = oi; }
                float ova = __shfl_xor(bva, off); int oia = __shfl_xor(bia, off);
                if (ova > bva || (ova == bva && oia < bia)) { bva = ova; bia = oia; }
            }
            if (lane == 0) { wbv[wid] = bv; wbi[wid] = bi; wbva[wid] = bva; wbia[wid] = bia; }
        }
        __syncthreads();
        if (tid == 0) {
            // combine waves in ascending index order: strict > keeps first occurrence
            float cv = -INFINITY; int ci = NNUM;
            float cva = -INFINITY; int cia = NNUM;
            #pragma unroll
            for (int w = 0; w < AW; ++w) {
                if (wbv[w] > cv)   { cv = wbv[w];   ci = wbi[w]; }
                if (wbva[w] > cva) { cva = wbva[w]; cia = wbia[w]; }
            }
            bool has = (cand[0] | cand[1] | cand[2] | cand[3] | cand[4]) != 0ULL;
            sh_has = has ? 1 : 0;
            if (has) {
                #pragma unroll
                for (int w = 0; w < AW; ++w) fin[w] = cand[w] & adj_sh[ci][w];
            } else {
                #pragma unroll
                for (int w = 0; w < AW; ++w)
                    fin[w] = ((cia >> 6) == w) ? (1ULL << (cia & 63)) : 0ULL;
            }
        }
        __syncthreads();
        if (sh_has) {
            for (int it = 0; it < NNUM + 2; ++it) {
                if (wid < AW) {
                    bool nb = false;
                    if (j < NNUM && cb) {
                        ull o = (adj_sh[j][0] & fin[0]) | (adj_sh[j][1] & fin[1]) |
                                (adj_sh[j][2] & fin[2]) | (adj_sh[j][3] & fin[3]) |
                                (adj_sh[j][4] & fin[4]);
                        nb = (o != 0ULL);        // adj symmetric: row j == column j
                    }
                    ull nball = __ballot(nb);
                    if (lane == 0) nwv[wid] = nball;
                }
                __syncthreads();
                if (wid == 0) {
                    bool ch = (lane < AW) && (nwv[lane] != fin[lane]);
                    ull chb = __ballot(ch);
                    if (lane == 0) sh_go = (chb != 0ULL) ? 1 : 0;
                    if (lane < AW) fin[lane] = nwv[lane];
                }
                __syncthreads();
                if (!sh_go) break;       // sh_go rewritten only after next barrier
            }
        }
        if (tid == 0) {
            int cs = 0;
            for (int w = 0; w < AW; ++w) cs += __popcll(fin[w]);
            sh_cf = (float)cs;
        }
        __syncthreads();
        // ---- meanmap into LDS (float4) ----
        if (tid < HW4) {
            float4 a = {0.f, 0.f, 0.f, 0.f};
            for (int w = 0; w < AW; ++w) {
                ull word = fin[w];
                while (word) {
                    int jj = w * 64 + (__ffsll(word) - 1);
                    word &= word - 1;
                    float4 r = ((const float4*)g_rm)[((size_t)b * NNUM + jj) * HW4 + tid];
                    a.x += r.x; a.y += r.y; a.z += r.z; a.w += r.w;
                }
            }
            float cdiv = sh_cf;
            float4 o;
            o.x = __fdiv_rn(a.x, cdiv); o.y = __fdiv_rn(a.y, cdiv);
            o.z = __fdiv_rn(a.z, cdiv); o.w = __fdiv_rn(a.w, cdiv);
            ((float4*)m)[tid] = o;
        }
        __syncthreads();
        // ---- BCE: 28 tiles, 2 per iteration across 14 waves ----
        int half = (tid >= 448) ? 1 : 0;
        int t448 = tid - half * 448;         // 0..447
        int r  = t448 / 28, jx = t448 - r * 28;
        float* rY = rowY + half * (RT * 28);
        int cp1 = c + 1;
        double accd = 0.0;
        for (int tt = 0; tt < 14; ++tt) {
            int tile = tt * 2 + half;
            int row0 = tile * RT;
            __syncthreads();                 // prev iteration's readers done
            {
                int oy = row0 + r;
                float iy = fmaf((float)oy, 0.0625f, -0.46875f);   // (oy+0.5)/16-0.5, exact
                float y0f = floorf(iy);
                float wy = iy - y0f;
                int y0 = (int)y0f;
                if (y0 < 0) { y0 = 0; wy = 0.0f; } else if (y0 > 26) { y0 = 26; wy = 1.0f; }
                float lo = m[y0 * 28 + jx], hi = m[y0 * 28 + 28 + jx];
                rY[t448] = lo + wy * (hi - lo);
            }
            __syncthreads();
            const int* gr = gt + ((size_t)b * GH + row0 + r) * GH;
            if (jx < 27) {
                float rY0 = rY[r * 28 + jx], rY1 = rY[r * 28 + jx + 1];
                float sl = rY1 - rY0;
                const int4* gp = (const int4*)(gr + 16 * jx + 8);
                #pragma unroll
                for (int q = 0; q < 4; ++q) {
                    int4 g4 = gp[q];
                    #pragma unroll
                    for (int uu = 0; uu < 4; ++uu) {
                        int k = q * 4 + uu;
                        int gv = (uu == 0) ? g4.x : (uu == 1) ? g4.y : (uu == 2) ? g4.z : g4.w;
                        float wk = fmaf((float)k, 0.0625f, 0.03125f);   // (2k+1)/32, exact
                        float pred = rY0 + wk * sl;
                        float xv = (gv == cp1) ? pred : 1.0f - pred;
                        float lg = __logf(fmaxf(xv, 1.175494351e-38f));
                        accd += (double)((xv > 0.0f) ? lg : -100.0f);
                    }
                }
            } else {
                #pragma unroll
                for (int side = 0; side < 2; ++side) {
                    float pred = rY[r * 28 + (side ? 27 : 0)];
                    const int4* gp = (const int4*)(gr + (side ? 440 : 0));
                    int4 a0 = gp[0], a1 = gp[1];
                    int np = (a0.x == cp1) + (a0.y == cp1) + (a0.z == cp1) + (a0.w == cp1)
                           + (a1.x == cp1) + (a1.y == cp1) + (a1.z == cp1) + (a1.w == cp1);
                    float om = 1.0f - pred;
                    float lgp = (pred > 0.0f) ? __logf(fmaxf(pred, 1.175494351e-38f)) : -100.0f;
                    float lgn = (om   > 0.0f) ? __logf(fmaxf(om,   1.175494351e-38f)) : -100.0f;
                    accd += (double)lgp * (double)np + (double)lgn * (double)(8 - np);
                }
            }
        }
        #pragma unroll
        for (int off = 32; off; off >>= 1) accd += __shfl_xor(accd, off);
        if (lane == 0) wsum[wid] = accd;
        __syncthreads();
        if (tid == 0) {
            double s = 0.0;
            #pragma unroll
            for (int w = 0; w < 14; ++w) s += wsum[w];
            atomicAdd(&g_accbc[bc].v, -s * (1.0 / (448.0 * 448.0)));   // own line per bc
            asm volatile("s_waitcnt vmcnt(0)" ::: "memory");            // add performed
        }
    }
    // ---- spread fenceless completion: 160 arrivals on one root line ----
    if (tid == 0) {
        sh_last = 0;
        int d = __hip_atomic_fetch_add(&g_bdone, 1, __ATOMIC_RELAXED, __HIP_MEMORY_SCOPE_AGENT);
        if (d == TOTBC - 1) {
            atomicExch(&g_bdone, 0);     // self-reset
            sh_last = 1;
        }
    }
    __syncthreads();
    if (sh_last) {
        if (tid == 0) sh_sa = 0;
        __syncthreads();
        double s = 0.0;
        if (tid < TOTBC) {
            // read+reset via RMW at the MALL: sees every prior add, leaves 0 for next launch
            ull bits = atomicExch((ull*)&g_accbc[tid].v, 0ULL);
            s = __longlong_as_double(bits);
            if (label[tid] != 0) atomicAdd(&sh_sa, 1);
        }
        #pragma unroll
        for (int off = 32; off; off >>= 1) s += __shfl_xor(s, off);
        if (lane == 0) wsum[wid] = s;
        __syncthreads();
        if (tid == 0) {
            double tot = 0.0;
            #pragma unroll
            for (int w = 0; w < 14; ++w) tot += wsum[w];
            out[0] = (float)(tot / (double)sh_sa);
        }
    }
}

extern "C" void kernel_launch(void* const* d_in, const int* in_sizes, int n_in,
                              void* d_out, int out_size, void* d_ws, size_t ws_size,
                              hipStream_t stream) {
    const float* smap  = (const float*)d_in[0];   // (L,B,N,784)
    const float* score = (const float*)d_in[1];   // (B,N,C)
    const int*   label = (const int*)d_in[2];     // (B,C)
    const int*   gt    = (const int*)d_in[3];     // (B,448,448)
    float* out = (float*)d_out;

    hipLaunchKernelGGL(k_rm,    dim3(BNUM * NNUM), dim3(256), 0, stream, smap);
    hipLaunchKernelGGL(k_adj,   dim3(BNUM * NNUM), dim3(320), 0, stream);
    hipLaunchKernelGGL(k_cmbce, dim3(TOTBC),       dim3(896), 0, stream, score, label, gt, out);
}

// Round 9
// 64.694 us; speedup vs baseline: 1.2853x; 1.2853x over previous
//
#include <hip/hip_runtime.h>
#include <math.h>

#define LNUM 6
#define BNUM 8
#define NNUM 300
#define CNUM 20
#define HW   784
#define HW4  196   // HW/4
#define GH   448
#define NW   16    // mask words per (b,n): permuted bit order (popcount-invariant)
#define AW   5     // adjacency row words (300 bits -> 5 x u64)
#define RT   16    // bce rows per tile
#define NTILE 28   // 448/16 tiles per (b,c)
#define TOTBC  (BNUM*CNUM)          // 160
#define TOTBLK (TOTBC*NTILE)        // 4480

typedef unsigned long long ull;

// ---- device scratch (every consumed entry rewritten each launch; counters/acc self-reset) ----
__device__ float g_rm [BNUM*NNUM*HW];
__device__ ull   g_T  [BNUM*NNUM*NW];
__device__ int   g_s  [BNUM*NNUM];
__device__ ull   g_adj[BNUM*NNUM*AW];
__device__ ull   g_mmA[TOTBC*392];   // meanmap as u64 pairs; ATOMIC-ONLY access (MALL-coherent)
// one 128-B cacheline per bc -> no cross-bc serialization
struct PadD { double v; double pad[15]; };
struct PadI { int v;    int    pad[31]; };
__device__ PadD g_accbc[TOTBC];   // f64 partial per bc; exchanged to 0 by final block
__device__ PadI g_flag [TOTBC];   // meanmap-ready flag; set by tile-0, reset by bc-last
__device__ PadI g_tdone[TOTBC];   // tile-done per bc; reset by bc-last
__device__ int  g_bdone = 0;      // root line; reset by final block

// One block per (b,n): mean over L (float4), relu, max-normalize, rm + bitmask + popcount.
__global__ void k_rm(const float* __restrict__ sm) {
    int bn  = blockIdx.x;
    int tid = threadIdx.x;               // 256
    int lane = tid & 63, wid = tid >> 6;
    __shared__ float wmax[4];
    __shared__ int   scount;
    if (tid == 0) scount = 0;
    const size_t lstr4 = (size_t)BNUM * NNUM * HW4;
    const float4* base = (const float4*)sm + (size_t)bn * HW4;
    bool act = tid < HW4;
    float4 v = {0.f, 0.f, 0.f, 0.f};
    if (act) {
        float4 a = {0.f, 0.f, 0.f, 0.f};
        #pragma unroll
        for (int l = 0; l < LNUM; ++l) {
            float4 x = base[(size_t)l * lstr4 + tid];
            a.x += x.x; a.y += x.y; a.z += x.z; a.w += x.w;
        }
        v.x = fmaxf(__fdiv_rn(a.x, 6.0f), 0.0f);
        v.y = fmaxf(__fdiv_rn(a.y, 6.0f), 0.0f);
        v.z = fmaxf(__fdiv_rn(a.z, 6.0f), 0.0f);
        v.w = fmaxf(__fdiv_rn(a.w, 6.0f), 0.0f);
    }
    float lm = fmaxf(fmaxf(v.x, v.y), fmaxf(v.z, v.w));
    #pragma unroll
    for (int off = 32; off; off >>= 1) lm = fmaxf(lm, __shfl_xor(lm, off));
    if (lane == 0) wmax[wid] = lm;
    __syncthreads();
    float mx = fmaxf(fmaxf(wmax[0], wmax[1]), fmaxf(wmax[2], wmax[3]));
    float d = mx + 1e-6f;
    float4 nv;
    nv.x = __fdiv_rn(v.x, d); nv.y = __fdiv_rn(v.y, d);
    nv.z = __fdiv_rn(v.z, d); nv.w = __fdiv_rn(v.w, d);
    if (act) ((float4*)g_rm)[(size_t)bn * HW4 + tid] = nv;
    float c[4] = {nv.x, nv.y, nv.z, nv.w};
    #pragma unroll
    for (int k = 0; k < 4; ++k) {
        bool pr = act && (c[k] > 0.7f);
        ull ball = __ballot(pr);
        if (lane == 0) {
            g_T[(size_t)bn * NW + k * 4 + wid] = ball;
            atomicAdd(&scount, __popcll(ball));
        }
    }
    __syncthreads();
    if (tid == 0) g_s[bn] = scount;
}

// One block per (b,i): adjacency row i via popcount(AND) + exact f32 (iou+dice)/2 > 0.5
__global__ void k_adj() {
    int blk = blockIdx.x;                // b*300 + i
    int b = blk / NNUM;
    int tid = threadIdx.x;               // 320 (5 waves)
    __shared__ ull Ti[NW];
    __shared__ int si_sh;
    if (tid < NW)  Ti[tid] = g_T[(size_t)blk * NW + tid];
    if (tid == NW) si_sh = g_s[blk];
    __syncthreads();
    bool a = false;
    int j = tid;
    if (j < NNUM) {
        const ull* Tj = &g_T[((size_t)b * NNUM + j) * NW];
        int inter = 0;
        #pragma unroll
        for (int w = 0; w < NW; ++w) inter += __popcll(Ti[w] & Tj[w]);
        int si = si_sh, sj = g_s[b * NNUM + j];
        int uni = si + sj - inter, tot = si + sj;
        float iou  = (uni == 0) ? 1.0f : __fdiv_rn((float)inter, (float)uni);
        float dice = (tot == 0) ? 1.0f : __fdiv_rn(2.0f * (float)inter, (float)tot);
        a = (0.5f * (iou + dice)) > 0.5f;
    }
    ull ball = __ballot(a);
    if ((tid & 63) == 0) g_adj[(size_t)blk * AW + (tid >> 6)] = ball;
}

// One block per (bc, tile), 448 threads. tile==0 runs the parallel cluster + meanmap
// and publishes via MALL atomics + flag; tiles 1..27 poll the flag (27 pollers per
// padded line). Then all 28 blocks do their 16-row BCE tile in parallel.
__global__ void __launch_bounds__(448)
k_cbce(const float* __restrict__ score, const int* __restrict__ label,
       const int* __restrict__ gt, float* __restrict__ out) {
    int blk = blockIdx.x;                // bc*NTILE + tile
    int bc = blk / NTILE, tile = blk - bc * NTILE;
    int b = bc / CNUM, c = bc - b * CNUM;
    int tid = threadIdx.x;               // 448 (7 waves)
    int lane = tid & 63, wid = tid >> 6;
    bool active = (label[bc] != 0);      // block-uniform

    __shared__ ull adj_sh[NNUM][AW];
    __shared__ ull cand[AW], fin[AW], nwv[AW];
    __shared__ float wbv[AW], wbva[AW];
    __shared__ int   wbi[AW], wbia[AW];
    __shared__ int sh_has, sh_go, sh_last, sh_sa;
    __shared__ float sh_cf;
    __shared__ float m[HW];
    __shared__ float rowY[RT * 28];
    __shared__ double wsum[7];

    if (active) {
        if (tile == 0) {
            // ---------- producer: parallel cluster ----------
            for (int idx = tid; idx < NNUM * AW; idx += 448)
                ((ull*)adj_sh)[idx] = g_adj[(size_t)b * NNUM * AW + idx];
            int j = tid;
            bool cb = false;
            if (wid < AW) {
                float sc = -INFINITY;
                if (j < NNUM) {
                    sc = score[((size_t)b * NNUM + j) * CNUM + c];
                    cb = sc > 0.01f;
                }
                ull ball = __ballot(cb);
                if (lane == 0) cand[wid] = ball;
                float bv  = cb ? sc : -INFINITY;          int bi  = cb ? j : NNUM;
                float bva = (j < NNUM) ? sc : -INFINITY;  int bia = (j < NNUM) ? j : NNUM;
                #pragma unroll
                for (int off = 1; off < 64; off <<= 1) {
                    float ov = __shfl_xor(bv, off);  int oi = __shfl_xor(bi, off);
                    if (ov > bv || (ov == bv && oi < bi)) { bv = ov; bi = oi; }
                    float ova = __shfl_xor(bva, off); int oia = __shfl_xor(bia, off);
                    if (ova > bva || (ova == bva && oia < bia)) { bva = ova; bia = oia; }
                }
                if (lane == 0) { wbv[wid] = bv; wbi[wid] = bi; wbva[wid] = bva; wbia[wid] = bia; }
            }
            __syncthreads();
            if (tid == 0) {
                // combine waves ascending: strict > keeps first occurrence
                float cv = -INFINITY; int ci = NNUM;
                float cva = -INFINITY; int cia = NNUM;
                #pragma unroll
                for (int w = 0; w < AW; ++w) {
                    if (wbv[w] > cv)   { cv = wbv[w];   ci = wbi[w]; }
                    if (wbva[w] > cva) { cva = wbva[w]; cia = wbia[w]; }
                }
                bool has = (cand[0] | cand[1] | cand[2] | cand[3] | cand[4]) != 0ULL;
                sh_has = has ? 1 : 0;
                if (has) {
                    #pragma unroll
                    for (int w = 0; w < AW; ++w) fin[w] = cand[w] & adj_sh[ci][w];
                } else {
                    #pragma unroll
                    for (int w = 0; w < AW; ++w)
                        fin[w] = ((cia >> 6) == w) ? (1ULL << (cia & 63)) : 0ULL;
                }
            }
            __syncthreads();
            if (sh_has) {
                for (int it = 0; it < NNUM + 2; ++it) {
                    if (wid < AW) {
                        bool nb = false;
                        if (j < NNUM && cb) {
                            ull o = (adj_sh[j][0] & fin[0]) | (adj_sh[j][1] & fin[1]) |
                                    (adj_sh[j][2] & fin[2]) | (adj_sh[j][3] & fin[3]) |
                                    (adj_sh[j][4] & fin[4]);
                            nb = (o != 0ULL);    // adj symmetric: row j == column j
                        }
                        ull nball = __ballot(nb);
                        if (lane == 0) nwv[wid] = nball;
                    }
                    __syncthreads();
                    if (wid == 0) {
                        bool ch = (lane < AW) && (nwv[lane] != fin[lane]);
                        ull chb = __ballot(ch);
                        if (lane == 0) sh_go = (chb != 0ULL) ? 1 : 0;
                        if (lane < AW) fin[lane] = nwv[lane];
                    }
                    __syncthreads();
                    if (!sh_go) break;   // sh_go rewritten only after next barrier
                }
            }
            if (tid == 0) {
                int cs = 0;
                for (int w = 0; w < AW; ++w) cs += __popcll(fin[w]);
                sh_cf = (float)cs;
            }
            __syncthreads();
            // ---------- meanmap -> LDS + MALL atomics ----------
            if (tid < HW4) {
                float4 a = {0.f, 0.f, 0.f, 0.f};
                for (int w = 0; w < AW; ++w) {
                    ull word = fin[w];
                    while (word) {
                        int jj = w * 64 + (__ffsll(word) - 1);
                        word &= word - 1;
                        float4 r = ((const float4*)g_rm)[((size_t)b * NNUM + jj) * HW4 + tid];
                        a.x += r.x; a.y += r.y; a.z += r.z; a.w += r.w;
                    }
                }
                float cdiv = sh_cf;
                float4 o;
                o.x = __fdiv_rn(a.x, cdiv); o.y = __fdiv_rn(a.y, cdiv);
                o.z = __fdiv_rn(a.z, cdiv); o.w = __fdiv_rn(a.w, cdiv);
                ((float4*)m)[tid] = o;
                ull w0 = ((ull)__float_as_uint(o.y) << 32) | __float_as_uint(o.x);
                ull w1 = ((ull)__float_as_uint(o.w) << 32) | __float_as_uint(o.z);
                atomicExch(&g_mmA[(size_t)bc * 392 + 2 * tid],     w0);  // RMW at MALL
                atomicExch(&g_mmA[(size_t)bc * 392 + 2 * tid + 1], w1);
            }
            __syncthreads();             // per-wave vmcnt drained -> all atomics performed
            if (tid == 0)
                __hip_atomic_store(&g_flag[bc].v, 1, __ATOMIC_RELAXED, __HIP_MEMORY_SCOPE_AGENT);
        } else {
            // ---------- waiter: poll flag, fetch meanmap from MALL ----------
            if (tid == 0) {
                while (__hip_atomic_load(&g_flag[bc].v, __ATOMIC_RELAXED,
                                         __HIP_MEMORY_SCOPE_AGENT) == 0)
                    __builtin_amdgcn_s_sleep(8);
            }
            __syncthreads();
            if (tid < 392) {
                ull w = __hip_atomic_load(&g_mmA[(size_t)bc * 392 + tid],
                                          __ATOMIC_RELAXED, __HIP_MEMORY_SCOPE_AGENT);
                m[2 * tid]     = __uint_as_float((unsigned)w);
                m[2 * tid + 1] = __uint_as_float((unsigned)(w >> 32));
            }
            __syncthreads();
        }
        // ---------- BCE tile (identical math to R7) ----------
        int row0 = tile * RT;
        {
            int r = tid / 28, x = tid - (tid / 28) * 28;
            int oy = row0 + r;
            float iy = fmaf((float)oy, 0.0625f, -0.46875f);   // (oy+0.5)/16-0.5, exact
            float y0f = floorf(iy);
            float wy = iy - y0f;
            int y0 = (int)y0f;
            if (y0 < 0) { y0 = 0; wy = 0.0f; } else if (y0 > 26) { y0 = 26; wy = 1.0f; }
            float lo = m[y0 * 28 + x], hi = m[y0 * 28 + 28 + x];
            rowY[tid] = lo + wy * (hi - lo);
        }
        __syncthreads();
        double acc = 0.0;
        {
            int r = tid / 28, jx = tid - (tid / 28) * 28;
            const int* gr = gt + ((size_t)b * GH + row0 + r) * GH;
            int cp1 = c + 1;
            if (jx < 27) {
                float rY0 = rowY[r * 28 + jx], rY1 = rowY[r * 28 + jx + 1];
                float sl = rY1 - rY0;
                const int4* gp = (const int4*)(gr + 16 * jx + 8);
                #pragma unroll
                for (int q = 0; q < 4; ++q) {
                    int4 g4 = gp[q];
                    #pragma unroll
                    for (int uu = 0; uu < 4; ++uu) {
                        int k = q * 4 + uu;
                        int gv = (uu == 0) ? g4.x : (uu == 1) ? g4.y : (uu == 2) ? g4.z : g4.w;
                        float wk = fmaf((float)k, 0.0625f, 0.03125f);   // (2k+1)/32, exact
                        float pred = rY0 + wk * sl;
                        float xv = (gv == cp1) ? pred : 1.0f - pred;
                        float lg = __logf(fmaxf(xv, 1.175494351e-38f));
                        acc += (double)((xv > 0.0f) ? lg : -100.0f);
                    }
                }
            } else {
                #pragma unroll
                for (int side = 0; side < 2; ++side) {
                    float pred = rowY[r * 28 + (side ? 27 : 0)];
                    const int4* gp = (const int4*)(gr + (side ? 440 : 0));
                    int4 a0 = gp[0], a1 = gp[1];
                    int np = (a0.x == cp1) + (a0.y == cp1) + (a0.z == cp1) + (a0.w == cp1)
                           + (a1.x == cp1) + (a1.y == cp1) + (a1.z == cp1) + (a1.w == cp1);
                    float om = 1.0f - pred;
                    float lgp = (pred > 0.0f) ? __logf(fmaxf(pred, 1.175494351e-38f)) : -100.0f;
                    float lgn = (om   > 0.0f) ? __logf(fmaxf(om,   1.175494351e-38f)) : -100.0f;
                    acc += (double)lgp * (double)np + (double)lgn * (double)(8 - np);
                }
            }
        }
        #pragma unroll
        for (int off = 32; off; off >>= 1) acc += __shfl_xor(acc, off);
        if (lane == 0) wsum[wid] = acc;
        __syncthreads();
        if (tid == 0) {
            double s = 0.0;
            #pragma unroll
            for (int w = 0; w < 7; ++w) s += wsum[w];
            atomicAdd(&g_accbc[bc].v, -s * (1.0 / (448.0 * 448.0)));   // own line per bc
            asm volatile("s_waitcnt vmcnt(0)" ::: "memory");            // add performed
        }
    }
    // ---- spread fenceless completion (R7 protocol + flag reset) ----
    if (tid == 0) {
        sh_last = 0;
        int t = __hip_atomic_fetch_add(&g_tdone[bc].v, 1, __ATOMIC_RELAXED, __HIP_MEMORY_SCOPE_AGENT);
        if (t == NTILE - 1) {            // 28th arrival of this bc
            atomicExch(&g_tdone[bc].v, 0);
            atomicExch(&g_flag[bc].v, 0);
            asm volatile("s_waitcnt vmcnt(0)" ::: "memory");
            int d = __hip_atomic_fetch_add(&g_bdone, 1, __ATOMIC_RELAXED, __HIP_MEMORY_SCOPE_AGENT);
            if (d == TOTBC - 1) {
                atomicExch(&g_bdone, 0);
                sh_last = 1;
            }
        }
    }
    __syncthreads();
    if (sh_last) {
        if (tid == 0) sh_sa = 0;
        __syncthreads();
        double s = 0.0;
        if (tid < TOTBC) {
            ull bits = atomicExch((ull*)&g_accbc[tid].v, 0ULL);   // read+reset at MALL
            s = __longlong_as_double(bits);
            if (label[tid] != 0) atomicAdd(&sh_sa, 1);
        }
        #pragma unroll
        for (int off = 32; off; off >>= 1) s += __shfl_xor(s, off);
        if (lane == 0) wsum[wid] = s;
        __syncthreads();
        if (tid == 0) {
            double tot = 0.0;
            #pragma unroll
            for (int w = 0; w < 7; ++w) tot += wsum[w];
            out[0] = (float)(tot / (double)sh_sa);
        }
    }
}

extern "C" void kernel_launch(void* const* d_in, const int* in_sizes, int n_in,
                              void* d_out, int out_size, void* d_ws, size_t ws_size,
                              hipStream_t stream) {
    const float* smap  = (const float*)d_in[0];   // (L,B,N,784)
    const float* score = (const float*)d_in[1];   // (B,N,C)
    const int*   label = (const int*)d_in[2];     // (B,C)
    const int*   gt    = (const int*)d_in[3];     // (B,448,448)
    float* out = (float*)d_out;

    hipLaunchKernelGGL(k_rm,   dim3(BNUM * NNUM), dim3(256), 0, stream, smap);
    hipLaunchKernelGGL(k_adj,  dim3(BNUM * NNUM), dim3(320), 0, stream);
    hipLaunchKernelGGL(k_cbce, dim3(TOTBLK),      dim3(448), 0, stream, score, label, gt, out);
}

// Round 10
// 61.413 us; speedup vs baseline: 1.3540x; 1.0534x over previous
//
#include <hip/hip_runtime.h>
#include <math.h>

#define LNUM 6
#define BNUM 8
#define NNUM 300
#define CNUM 20
#define HW   784
#define HW4  196   // HW/4
#define GH   448
#define NW   16    // mask words per (b,n): permuted bit order (popcount-invariant)
#define AW   5     // adjacency row words (300 bits -> 5 x u64)
#define RT   16    // bce rows per tile
#define NTILE 28   // 448/16 tiles per b
#define TOTBC  (BNUM*CNUM)          // 160
#define BCEBLK (BNUM*NTILE)         // 224

typedef unsigned long long ull;

// ---- device scratch (every consumed entry rewritten each launch; counters/acc self-reset) ----
__device__ float g_rm [BNUM*NNUM*HW];
__device__ ull   g_T  [BNUM*NNUM*NW];
__device__ int   g_s  [BNUM*NNUM];
__device__ ull   g_adj[BNUM*NNUM*AW];
__device__ float g_mm [TOTBC*HW];
// one 128-B cacheline per entry -> no cross-entry atomic serialization
struct PadD { double v; double pad[15]; };
struct PadI { int v;    int    pad[31]; };
__device__ PadD g_accb [BNUM];    // f64 partial per b; exchanged to 0 by final block
__device__ PadI g_tdone[BNUM];    // tile-done per b (28 arrivals); reset by b-last
__device__ int  g_bdone = 0;      // root line (8 arrivals); reset by final block

// One block per (b,n): mean over L (float4), relu, max-normalize, rm + bitmask + popcount.
__global__ void k_rm(const float* __restrict__ sm) {
    int bn  = blockIdx.x;
    int tid = threadIdx.x;               // 256
    int lane = tid & 63, wid = tid >> 6;
    __shared__ float wmax[4];
    __shared__ int   scount;
    if (tid == 0) scount = 0;
    const size_t lstr4 = (size_t)BNUM * NNUM * HW4;
    const float4* base = (const float4*)sm + (size_t)bn * HW4;
    bool act = tid < HW4;
    float4 v = {0.f, 0.f, 0.f, 0.f};
    if (act) {
        float4 a = {0.f, 0.f, 0.f, 0.f};
        #pragma unroll
        for (int l = 0; l < LNUM; ++l) {
            float4 x = base[(size_t)l * lstr4 + tid];
            a.x += x.x; a.y += x.y; a.z += x.z; a.w += x.w;
        }
        v.x = fmaxf(__fdiv_rn(a.x, 6.0f), 0.0f);
        v.y = fmaxf(__fdiv_rn(a.y, 6.0f), 0.0f);
        v.z = fmaxf(__fdiv_rn(a.z, 6.0f), 0.0f);
        v.w = fmaxf(__fdiv_rn(a.w, 6.0f), 0.0f);
    }
    float lm = fmaxf(fmaxf(v.x, v.y), fmaxf(v.z, v.w));
    #pragma unroll
    for (int off = 32; off; off >>= 1) lm = fmaxf(lm, __shfl_xor(lm, off));
    if (lane == 0) wmax[wid] = lm;
    __syncthreads();
    float mx = fmaxf(fmaxf(wmax[0], wmax[1]), fmaxf(wmax[2], wmax[3]));
    float d = mx + 1e-6f;
    float4 nv;
    nv.x = __fdiv_rn(v.x, d); nv.y = __fdiv_rn(v.y, d);
    nv.z = __fdiv_rn(v.z, d); nv.w = __fdiv_rn(v.w, d);
    if (act) ((float4*)g_rm)[(size_t)bn * HW4 + tid] = nv;
    float c[4] = {nv.x, nv.y, nv.z, nv.w};
    #pragma unroll
    for (int k = 0; k < 4; ++k) {
        bool pr = act && (c[k] > 0.7f);
        ull ball = __ballot(pr);
        if (lane == 0) {
            g_T[(size_t)bn * NW + k * 4 + wid] = ball;
            atomicAdd(&scount, __popcll(ball));
        }
    }
    __syncthreads();
    if (tid == 0) g_s[bn] = scount;
}

// One block per (b,i): adjacency row i via popcount(AND) + exact f32 (iou+dice)/2 > 0.5
__global__ void k_adj() {
    int blk = blockIdx.x;                // b*300 + i
    int b = blk / NNUM;
    int tid = threadIdx.x;               // 320 (5 waves)
    __shared__ ull Ti[NW];
    __shared__ int si_sh;
    if (tid < NW)  Ti[tid] = g_T[(size_t)blk * NW + tid];
    if (tid == NW) si_sh = g_s[blk];
    __syncthreads();
    bool a = false;
    int j = tid;
    if (j < NNUM) {
        const ull* Tj = &g_T[((size_t)b * NNUM + j) * NW];
        int inter = 0;
        #pragma unroll
        for (int w = 0; w < NW; ++w) inter += __popcll(Ti[w] & Tj[w]);
        int si = si_sh, sj = g_s[b * NNUM + j];
        int uni = si + sj - inter, tot = si + sj;
        float iou  = (uni == 0) ? 1.0f : __fdiv_rn((float)inter, (float)uni);
        float dice = (tot == 0) ? 1.0f : __fdiv_rn(2.0f * (float)inter, (float)tot);
        a = (0.5f * (iou + dice)) > 0.5f;
    }
    ull ball = __ballot(a);
    if ((tid & 63) == 0) g_adj[(size_t)blk * AW + (tid >> 6)] = ball;
}

// One block per active (b,c), 320 threads: FULLY PARALLEL cluster fixed point + float4 meanmap.
__global__ void __launch_bounds__(320)
k_cm(const float* __restrict__ score, const int* __restrict__ label) {
    int blk = blockIdx.x;                // b*C + c
    if (label[blk] == 0) return;         // block-uniform, before any barrier
    int b = blk / CNUM, c = blk - b * CNUM;
    int tid = threadIdx.x;               // 320 (5 waves)
    int lane = tid & 63, wid = tid >> 6;
    __shared__ ull adj_sh[NNUM][AW];
    __shared__ ull cand[AW], fin[AW], nwv[AW];
    __shared__ float wbv[AW], wbva[AW];
    __shared__ int   wbi[AW], wbia[AW];
    __shared__ int sh_has, sh_go;
    __shared__ float sh_cf;
    for (int idx = tid; idx < NNUM * AW; idx += 320)
        ((ull*)adj_sh)[idx] = g_adj[(size_t)b * NNUM * AW + idx];
    int j = tid;
    bool cb = false;
    float sc = -INFINITY;
    if (j < NNUM) {
        sc = score[((size_t)b * NNUM + j) * CNUM + c];
        cb = sc > 0.01f;
    }
    ull ball = __ballot(cb);
    if (lane == 0) cand[wid] = ball;
    float bv  = cb ? sc : -INFINITY;          int bi  = cb ? j : NNUM;
    float bva = (j < NNUM) ? sc : -INFINITY;  int bia = (j < NNUM) ? j : NNUM;
    #pragma unroll
    for (int off = 1; off < 64; off <<= 1) {
        float ov = __shfl_xor(bv, off);  int oi = __shfl_xor(bi, off);
        if (ov > bv || (ov == bv && oi < bi)) { bv = ov; bi = oi; }
        float ova = __shfl_xor(bva, off); int oia = __shfl_xor(bia, off);
        if (ova > bva || (ova == bva && oia < bia)) { bva = ova; bia = oia; }
    }
    if (lane == 0) { wbv[wid] = bv; wbi[wid] = bi; wbva[wid] = bva; wbia[wid] = bia; }
    __syncthreads();
    if (tid == 0) {
        float cv = -INFINITY; int ci = NNUM;
        float cva = -INFINITY; int cia = NNUM;
        #pragma unroll
        for (int w = 0; w < AW; ++w) {
            if (wbv[w] > cv)   { cv = wbv[w];   ci = wbi[w]; }
            if (wbva[w] > cva) { cva = wbva[w]; cia = wbia[w]; }
        }
        bool has = (cand[0] | cand[1] | cand[2] | cand[3] | cand[4]) != 0ULL;
        sh_has = has ? 1 : 0;
        if (has) {
            #pragma unroll
            for (int w = 0; w < AW; ++w) fin[w] = cand[w] & adj_sh[ci][w];
        } else {
            #pragma unroll
            for (int w = 0; w < AW; ++w)
                fin[w] = ((cia >> 6) == w) ? (1ULL << (cia & 63)) : 0ULL;
        }
    }
    __syncthreads();
    if (sh_has) {
        for (int it = 0; it < NNUM + 2; ++it) {
            bool nb = false;
            if (j < NNUM && cb) {
                ull o = (adj_sh[j][0] & fin[0]) | (adj_sh[j][1] & fin[1]) |
                        (adj_sh[j][2] & fin[2]) | (adj_sh[j][3] & fin[3]) |
                        (adj_sh[j][4] & fin[4]);
                nb = (o != 0ULL);         // adj symmetric: row j == column j
            }
            ull nball = __ballot(nb);
            if (lane == 0) nwv[wid] = nball;
            __syncthreads();
            if (wid == 0) {
                bool ch = (lane < AW) && (nwv[lane] != fin[lane]);
                ull chb = __ballot(ch);
                if (lane == 0) sh_go = (chb != 0ULL) ? 1 : 0;
                if (lane < AW) fin[lane] = nwv[lane];
            }
            __syncthreads();
            if (!sh_go) break;            // sh_go rewritten only after next barrier
        }
    }
    if (tid == 0) {
        int cs = 0;
        for (int w = 0; w < AW; ++w) cs += __popcll(fin[w]);
        sh_cf = (float)cs;
    }
    __syncthreads();
    if (tid < HW4) {
        float4 a = {0.f, 0.f, 0.f, 0.f};
        for (int w = 0; w < AW; ++w) {
            ull word = fin[w];
            while (word) {
                int jj = w * 64 + (__ffsll(word) - 1);
                word &= word - 1;
                float4 r = ((const float4*)g_rm)[((size_t)b * NNUM + jj) * HW4 + tid];
                a.x += r.x; a.y += r.y; a.z += r.z; a.w += r.w;
            }
        }
        float cdiv = sh_cf;
        float4 o;
        o.x = __fdiv_rn(a.x, cdiv); o.y = __fdiv_rn(a.y, cdiv);
        o.z = __fdiv_rn(a.z, cdiv); o.w = __fdiv_rn(a.w, cdiv);
        ((float4*)g_mm)[(size_t)blk * HW4 + tid] = o;
    }
}

// One block per (b, tile), 896 threads: gt tile staged ONCE to LDS (u8), then loop
// over the 20 classes (label-guarded, barrier-uniform: 10 per thread-half parity).
// rowY per class from L2-hot g_mm; identical per-pixel math to R7. Fenceless
// hierarchical finalization (per-b lines -> 8-arrival root).
__global__ void __launch_bounds__(896)
k_bce(const int* __restrict__ gt, const int* __restrict__ label, float* __restrict__ out) {
    int blk = blockIdx.x;                // b*NTILE + tile
    int b = blk / NTILE, tile = blk - b * NTILE;
    int tid = threadIdx.x;               // 896 (14 waves)
    int lane = tid & 63, wid = tid >> 6;
    int half = (tid >= 448) ? 1 : 0;
    int t448 = tid - half * 448;         // 0..447
    int r  = t448 / 28, jx = t448 - r * 28;
    int row0 = tile * RT;

    __shared__ unsigned char gtb[RT * GH];   // 7168 B: gt tile as u8 (values 0..20)
    __shared__ float rowY[2][RT * 28];
    __shared__ double wsum[14];
    __shared__ int sh_last, sh_sa;

    // ---- stage gt tile once: 1792 int4 across 896 threads ----
    {
        const int4* gp = (const int4*)(gt + (size_t)b * GH * GH + (size_t)row0 * GH);
        #pragma unroll
        for (int q = 0; q < 2; ++q) {
            int idx = q * 896 + tid;     // < 1792
            int4 g4 = gp[idx];
            int base = idx * 4;
            gtb[base]     = (unsigned char)g4.x;
            gtb[base + 1] = (unsigned char)g4.y;
            gtb[base + 2] = (unsigned char)g4.z;
            gtb[base + 3] = (unsigned char)g4.w;
        }
    }
    double accd = 0.0;
    // ---- 10 uniform iterations per parity (20 classes total) ----
    for (int cc = 0; cc < 10; ++cc) {
        int c = 2 * cc + half;
        int bc = b * CNUM + c;
        bool lab = (label[bc] != 0);     // uniform within each half
        __syncthreads();                 // protect rowY from previous iteration's readers
        if (lab) {
            int oy = row0 + r;
            float iy = fmaf((float)oy, 0.0625f, -0.46875f);   // (oy+0.5)/16-0.5, exact
            float y0f = floorf(iy);
            float wy = iy - y0f;
            int y0 = (int)y0f;
            if (y0 < 0) { y0 = 0; wy = 0.0f; } else if (y0 > 26) { y0 = 26; wy = 1.0f; }
            const float* mp = g_mm + (size_t)bc * HW + y0 * 28 + jx;
            float lo = mp[0], hi = mp[28];
            rowY[half][t448] = lo + wy * (hi - lo);
        }
        __syncthreads();
        if (lab) {
            int cp1 = c + 1;
            if (jx < 27) {
                float rY0 = rowY[half][t448], rY1 = rowY[half][t448 + 1];
                float sl = rY1 - rY0;
                int base = r * GH + 16 * jx + 8;           // u32-aligned
                #pragma unroll
                for (int q = 0; q < 4; ++q) {
                    unsigned w4 = *(const unsigned*)(gtb + base + 4 * q);
                    #pragma unroll
                    for (int uu = 0; uu < 4; ++uu) {
                        int k = q * 4 + uu;
                        int gv = (w4 >> (8 * uu)) & 255;
                        float wk = fmaf((float)k, 0.0625f, 0.03125f);   // (2k+1)/32, exact
                        float pred = rY0 + wk * sl;
                        float xv = (gv == cp1) ? pred : 1.0f - pred;
                        float lg = __logf(fmaxf(xv, 1.175494351e-38f));
                        accd += (double)((xv > 0.0f) ? lg : -100.0f);
                    }
                }
            } else {
                #pragma unroll
                for (int side = 0; side < 2; ++side) {
                    float pred = rowY[half][r * 28 + (side ? 27 : 0)];
                    int base = r * GH + (side ? 440 : 0);
                    unsigned w0 = *(const unsigned*)(gtb + base);
                    unsigned w1 = *(const unsigned*)(gtb + base + 4);
                    int np = 0;
                    #pragma unroll
                    for (int uu = 0; uu < 4; ++uu) {
                        np += (((w0 >> (8 * uu)) & 255) == (unsigned)cp1);
                        np += (((w1 >> (8 * uu)) & 255) == (unsigned)cp1);
                    }
                    float om = 1.0f - pred;
                    float lgp = (pred > 0.0f) ? __logf(fmaxf(pred, 1.175494351e-38f)) : -100.0f;
                    float lgn = (om   > 0.0f) ? __logf(fmaxf(om,   1.175494351e-38f)) : -100.0f;
                    accd += (double)lgp * (double)np + (double)lgn * (double)(8 - np);
                }
            }
        }
    }
    #pragma unroll
    for (int off = 32; off; off >>= 1) accd += __shfl_xor(accd, off);
    if (lane == 0) wsum[wid] = accd;
    __syncthreads();
    if (tid == 0) {
        double s = 0.0;
        #pragma unroll
        for (int w = 0; w < 14; ++w) s += wsum[w];
        atomicAdd(&g_accb[b].v, -s * (1.0 / (448.0 * 448.0)));   // own line per b
        asm volatile("s_waitcnt vmcnt(0)" ::: "memory");          // add performed
        sh_last = 0;
        int t = __hip_atomic_fetch_add(&g_tdone[b].v, 1, __ATOMIC_RELAXED, __HIP_MEMORY_SCOPE_AGENT);
        if (t == NTILE - 1) {            // 28th tile of this b
            atomicExch(&g_tdone[b].v, 0);
            asm volatile("s_waitcnt vmcnt(0)" ::: "memory");
            int d = __hip_atomic_fetch_add(&g_bdone, 1, __ATOMIC_RELAXED, __HIP_MEMORY_SCOPE_AGENT);
            if (d == BNUM - 1) {
                atomicExch(&g_bdone, 0);
                sh_last = 1;
            }
        }
    }
    __syncthreads();
    if (sh_last) {
        if (tid == 0) sh_sa = 0;
        __syncthreads();
        double s = 0.0;
        if (tid < BNUM) {
            ull bits = atomicExch((ull*)&g_accb[tid].v, 0ULL);   // read+reset at MALL
            s = __longlong_as_double(bits);
        }
        if (tid < TOTBC && label[tid] != 0) atomicAdd(&sh_sa, 1);
        #pragma unroll
        for (int off = 32; off; off >>= 1) s += __shfl_xor(s, off);
        if (lane == 0) wsum[wid] = s;
        __syncthreads();
        if (tid == 0) {
            double tot = 0.0;
            #pragma unroll
            for (int w = 0; w < 14; ++w) tot += wsum[w];
            out[0] = (float)(tot / (double)sh_sa);
        }
    }
}

extern "C" void kernel_launch(void* const* d_in, const int* in_sizes, int n_in,
                              void* d_out, int out_size, void* d_ws, size_t ws_size,
                              hipStream_t stream) {
    const float* smap  = (const float*)d_in[0];   // (L,B,N,784)
    const float* score = (const float*)d_in[1];   // (B,N,C)
    const int*   label = (const int*)d_in[2];     // (B,C)
    const int*   gt    = (const int*)d_in[3];     // (B,448,448)
    float* out = (float*)d_out;

    hipLaunchKernelGGL(k_rm,  dim3(BNUM * NNUM), dim3(256), 0, stream, smap);
    hipLaunchKernelGGL(k_adj, dim3(BNUM * NNUM), dim3(320), 0, stream);
    hipLaunchKernelGGL(k_cm,  dim3(TOTBC),       dim3(320), 0, stream, score, label);
    hipLaunchKernelGGL(k_bce, dim3(BCEBLK),      dim3(896), 0, stream, gt, label, out);
}

// Round 11
// 57.100 us; speedup vs baseline: 1.4563x; 1.0755x over previous
//
#include <hip/hip_runtime.h>
#include <math.h>

#define LNUM 6
#define BNUM 8
#define NNUM 300
#define CNUM 20
#define HW   784
#define HW4  196   // HW/4
#define GH   448
#define NW   16    // mask words per (b,n): permuted bit order (popcount-invariant)
#define AW   5     // adjacency row words (300 bits -> 5 x u64)
#define RT   16    // rows per bce tile
#define NT2  14    // tile-PAIRS per bc (28 tiles / 2)
#define TOTBC  (BNUM*CNUM)          // 160
#define RM_UNITS (BNUM*NNUM)        // 2400
#define CVT_BLKS 392                // gt->u8 converter blocks (1605632 ints / 4096)
#define BCEBLK  (TOTBC*NT2)         // 2240

typedef unsigned long long ull;

// ---- device scratch (every consumed entry rewritten each launch; counters/acc self-reset) ----
__device__ float         g_rm [BNUM*NNUM*HW];
__device__ ull           g_T  [BNUM*NNUM*NW];
__device__ int           g_s  [BNUM*NNUM];
__device__ ull           g_adj[BNUM*NNUM*AW];
__device__ float         g_mm [TOTBC*HW];
__device__ unsigned char g_gt8[BNUM*GH*GH];   // gt as u8 (values 0..20), L2-resident
// one 128-B cacheline per entry -> no cross-entry atomic serialization
struct PadD { double v; double pad[15]; };
struct PadI { int v;    int    pad[31]; };
__device__ PadD g_accbc[TOTBC];   // f64 partial per bc; exchanged to 0 by final block
__device__ PadI g_tdone[TOTBC];   // tile-pair-done per bc (14 arrivals); reset by bc-last
__device__ int  g_bdone = 0;      // root line (160 arrivals); reset by final block

// Blocks 0..2399: per-(b,n) mean over L (float4), relu, max-normalize, rm + mask bits.
// Blocks 2400..2791: independent gt int32 -> u8 conversion (no extra graph node).
__global__ void k_rm(const float* __restrict__ sm, const int* __restrict__ gt) {
    int bn  = blockIdx.x;
    int tid = threadIdx.x;               // 256
    if (bn >= RM_UNITS) {
        int g = bn - RM_UNITS;           // 0..391, each handles 4096 ints
        const int4* gp = (const int4*)gt + (size_t)g * 1024;
        unsigned* op = (unsigned*)g_gt8 + (size_t)g * 1024;
        #pragma unroll
        for (int q = 0; q < 4; ++q) {
            int idx = q * 256 + tid;
            int4 v = gp[idx];
            unsigned w = (unsigned)(v.x & 255) | ((unsigned)(v.y & 255) << 8) |
                         ((unsigned)(v.z & 255) << 16) | ((unsigned)(v.w & 255) << 24);
            op[idx] = w;
        }
        return;
    }
    int lane = tid & 63, wid = tid >> 6;
    __shared__ float wmax[4];
    __shared__ int   scount;
    if (tid == 0) scount = 0;
    const size_t lstr4 = (size_t)BNUM * NNUM * HW4;
    const float4* base = (const float4*)sm + (size_t)bn * HW4;
    bool act = tid < HW4;
    float4 v = {0.f, 0.f, 0.f, 0.f};
    if (act) {
        float4 a = {0.f, 0.f, 0.f, 0.f};
        #pragma unroll
        for (int l = 0; l < LNUM; ++l) {
            float4 x = base[(size_t)l * lstr4 + tid];
            a.x += x.x; a.y += x.y; a.z += x.z; a.w += x.w;
        }
        v.x = fmaxf(__fdiv_rn(a.x, 6.0f), 0.0f);
        v.y = fmaxf(__fdiv_rn(a.y, 6.0f), 0.0f);
        v.z = fmaxf(__fdiv_rn(a.z, 6.0f), 0.0f);
        v.w = fmaxf(__fdiv_rn(a.w, 6.0f), 0.0f);
    }
    float lm = fmaxf(fmaxf(v.x, v.y), fmaxf(v.z, v.w));
    #pragma unroll
    for (int off = 32; off; off >>= 1) lm = fmaxf(lm, __shfl_xor(lm, off));
    if (lane == 0) wmax[wid] = lm;
    __syncthreads();
    float mx = fmaxf(fmaxf(wmax[0], wmax[1]), fmaxf(wmax[2], wmax[3]));
    float d = mx + 1e-6f;
    float4 nv;
    nv.x = __fdiv_rn(v.x, d); nv.y = __fdiv_rn(v.y, d);
    nv.z = __fdiv_rn(v.z, d); nv.w = __fdiv_rn(v.w, d);
    if (act) ((float4*)g_rm)[(size_t)bn * HW4 + tid] = nv;
    float c[4] = {nv.x, nv.y, nv.z, nv.w};
    #pragma unroll
    for (int k = 0; k < 4; ++k) {
        bool pr = act && (c[k] > 0.7f);
        ull ball = __ballot(pr);
        if (lane == 0) {
            g_T[(size_t)bn * NW + k * 4 + wid] = ball;
            atomicAdd(&scount, __popcll(ball));
        }
    }
    __syncthreads();
    if (tid == 0) g_s[bn] = scount;
}

// One block per (b,i): adjacency row i via popcount(AND) + exact f32 (iou+dice)/2 > 0.5
__global__ void k_adj() {
    int blk = blockIdx.x;                // b*300 + i
    int b = blk / NNUM;
    int tid = threadIdx.x;               // 320 (5 waves)
    __shared__ ull Ti[NW];
    __shared__ int si_sh;
    if (tid < NW)  Ti[tid] = g_T[(size_t)blk * NW + tid];
    if (tid == NW) si_sh = g_s[blk];
    __syncthreads();
    bool a = false;
    int j = tid;
    if (j < NNUM) {
        const ull* Tj = &g_T[((size_t)b * NNUM + j) * NW];
        int inter = 0;
        #pragma unroll
        for (int w = 0; w < NW; ++w) inter += __popcll(Ti[w] & Tj[w]);
        int si = si_sh, sj = g_s[b * NNUM + j];
        int uni = si + sj - inter, tot = si + sj;
        float iou  = (uni == 0) ? 1.0f : __fdiv_rn((float)inter, (float)uni);
        float dice = (tot == 0) ? 1.0f : __fdiv_rn(2.0f * (float)inter, (float)tot);
        a = (0.5f * (iou + dice)) > 0.5f;
    }
    ull ball = __ballot(a);
    if ((tid & 63) == 0) g_adj[(size_t)blk * AW + (tid >> 6)] = ball;
}

// One block per active (b,c), 320 threads: FULLY PARALLEL cluster fixed point + float4 meanmap.
__global__ void __launch_bounds__(320)
k_cm(const float* __restrict__ score, const int* __restrict__ label) {
    int blk = blockIdx.x;                // b*C + c
    if (label[blk] == 0) return;         // block-uniform, before any barrier
    int b = blk / CNUM, c = blk - b * CNUM;
    int tid = threadIdx.x;               // 320 (5 waves)
    int lane = tid & 63, wid = tid >> 6;
    __shared__ ull adj_sh[NNUM][AW];
    __shared__ ull cand[AW], fin[AW], nwv[AW];
    __shared__ float wbv[AW], wbva[AW];
    __shared__ int   wbi[AW], wbia[AW];
    __shared__ int sh_has, sh_go;
    __shared__ float sh_cf;
    for (int idx = tid; idx < NNUM * AW; idx += 320)
        ((ull*)adj_sh)[idx] = g_adj[(size_t)b * NNUM * AW + idx];
    int j = tid;
    bool cb = false;
    float sc = -INFINITY;
    if (j < NNUM) {
        sc = score[((size_t)b * NNUM + j) * CNUM + c];
        cb = sc > 0.01f;
    }
    ull ball = __ballot(cb);
    if (lane == 0) cand[wid] = ball;
    float bv  = cb ? sc : -INFINITY;          int bi  = cb ? j : NNUM;
    float bva = (j < NNUM) ? sc : -INFINITY;  int bia = (j < NNUM) ? j : NNUM;
    #pragma unroll
    for (int off = 1; off < 64; off <<= 1) {
        float ov = __shfl_xor(bv, off);  int oi = __shfl_xor(bi, off);
        if (ov > bv || (ov == bv && oi < bi)) { bv = ov; bi = oi; }
        float ova = __shfl_xor(bva, off); int oia = __shfl_xor(bia, off);
        if (ova > bva || (ova == bva && oia < bia)) { bva = ova; bia = oia; }
    }
    if (lane == 0) { wbv[wid] = bv; wbi[wid] = bi; wbva[wid] = bva; wbia[wid] = bia; }
    __syncthreads();
    if (tid == 0) {
        float cv = -INFINITY; int ci = NNUM;
        float cva = -INFINITY; int cia = NNUM;
        #pragma unroll
        for (int w = 0; w < AW; ++w) {
            if (wbv[w] > cv)   { cv = wbv[w];   ci = wbi[w]; }
            if (wbva[w] > cva) { cva = wbva[w]; cia = wbia[w]; }
        }
        bool has = (cand[0] | cand[1] | cand[2] | cand[3] | cand[4]) != 0ULL;
        sh_has = has ? 1 : 0;
        if (has) {
            #pragma unroll
            for (int w = 0; w < AW; ++w) fin[w] = cand[w] & adj_sh[ci][w];
        } else {
            #pragma unroll
            for (int w = 0; w < AW; ++w)
                fin[w] = ((cia >> 6) == w) ? (1ULL << (cia & 63)) : 0ULL;
        }
    }
    __syncthreads();
    if (sh_has) {
        for (int it = 0; it < NNUM + 2; ++it) {
            bool nb = false;
            if (j < NNUM && cb) {
                ull o = (adj_sh[j][0] & fin[0]) | (adj_sh[j][1] & fin[1]) |
                        (adj_sh[j][2] & fin[2]) | (adj_sh[j][3] & fin[3]) |
                        (adj_sh[j][4] & fin[4]);
                nb = (o != 0ULL);         // adj symmetric: row j == column j
            }
            ull nball = __ballot(nb);
            if (lane == 0) nwv[wid] = nball;
            __syncthreads();
            if (wid == 0) {
                bool ch = (lane < AW) && (nwv[lane] != fin[lane]);
                ull chb = __ballot(ch);
                if (lane == 0) sh_go = (chb != 0ULL) ? 1 : 0;
                if (lane < AW) fin[lane] = nwv[lane];
            }
            __syncthreads();
            if (!sh_go) break;            // sh_go rewritten only after next barrier
        }
    }
    if (tid == 0) {
        int cs = 0;
        for (int w = 0; w < AW; ++w) cs += __popcll(fin[w]);
        sh_cf = (float)cs;
    }
    __syncthreads();
    if (tid < HW4) {
        float4 a = {0.f, 0.f, 0.f, 0.f};
        for (int w = 0; w < AW; ++w) {
            ull word = fin[w];
            while (word) {
                int jj = w * 64 + (__ffsll(word) - 1);
                word &= word - 1;
                float4 r = ((const float4*)g_rm)[((size_t)b * NNUM + jj) * HW4 + tid];
                a.x += r.x; a.y += r.y; a.z += r.z; a.w += r.w;
            }
        }
        float cdiv = sh_cf;
        float4 o;
        o.x = __fdiv_rn(a.x, cdiv); o.y = __fdiv_rn(a.y, cdiv);
        o.z = __fdiv_rn(a.z, cdiv); o.w = __fdiv_rn(a.w, cdiv);
        ((float4*)g_mm)[(size_t)blk * HW4 + tid] = o;
    }
}

// One block per (bc, tile-pair): stage m once, process 2 x 16-row tiles with u8 gt.
// Fenceless hierarchical finalization (14 -> 160 arrivals), all self-resetting.
__global__ void __launch_bounds__(448)
k_bce(const int* __restrict__ label, float* __restrict__ out) {
    int blk = blockIdx.x;                // bc*NT2 + tt
    int bc = blk / NT2, tt = blk - bc * NT2;
    int tid = threadIdx.x;               // 448 (7 waves)
    int lane = tid & 63, wid = tid >> 6;
    __shared__ float m[HW];
    __shared__ float rowY[RT * 28];
    __shared__ double wsum[7];
    __shared__ int sh_last, sh_sa;
    bool active = (label[bc] != 0);      // block-uniform
    if (active) {
        int b = bc / CNUM, c = bc - b * CNUM;
        int cp1 = c + 1;
        int r = tid / 28, jx = tid - (tid / 28) * 28;
        if (tid < HW4) ((float4*)m)[tid] = ((const float4*)g_mm)[(size_t)bc * HW4 + tid];
        double acc = 0.0;
        #pragma unroll
        for (int t2 = 0; t2 < 2; ++t2) {
            int tile = tt * 2 + t2;
            int row0 = tile * RT;
            __syncthreads();             // m ready / prev rowY readers done
            {
                int oy = row0 + r;
                float iy = fmaf((float)oy, 0.0625f, -0.46875f);   // (oy+0.5)/16-0.5, exact
                float y0f = floorf(iy);
                float wy = iy - y0f;
                int y0 = (int)y0f;
                if (y0 < 0) { y0 = 0; wy = 0.0f; } else if (y0 > 26) { y0 = 26; wy = 1.0f; }
                float lo = m[y0 * 28 + jx], hi = m[y0 * 28 + 28 + jx];
                rowY[tid] = lo + wy * (hi - lo);
            }
            __syncthreads();
            const unsigned char* g8 = g_gt8 + ((size_t)b * GH + row0 + r) * GH;
            if (jx < 27) {
                float rY0 = rowY[tid], rY1 = rowY[tid + 1];
                float sl = rY1 - rY0;
                ull w0 = *(const ull*)(g8 + 16 * jx + 8);    // 8-aligned
                ull w1 = *(const ull*)(g8 + 16 * jx + 16);
                #pragma unroll
                for (int k = 0; k < 16; ++k) {
                    int gv = (int)((k < 8 ? (w0 >> (8 * k)) : (w1 >> (8 * (k - 8)))) & 255);
                    float wk = fmaf((float)k, 0.0625f, 0.03125f);   // (2k+1)/32, exact
                    float pred = rY0 + wk * sl;
                    float xv = (gv == cp1) ? pred : 1.0f - pred;
                    float lg = __logf(fmaxf(xv, 1.175494351e-38f));
                    acc += (double)((xv > 0.0f) ? lg : -100.0f);
                }
            } else {
                #pragma unroll
                for (int side = 0; side < 2; ++side) {
                    float pred = rowY[r * 28 + (side ? 27 : 0)];
                    ull w = *(const ull*)(g8 + (side ? 440 : 0));
                    int np = 0;
                    #pragma unroll
                    for (int uu = 0; uu < 8; ++uu)
                        np += (((w >> (8 * uu)) & 255) == (unsigned)cp1);
                    float om = 1.0f - pred;
                    float lgp = (pred > 0.0f) ? __logf(fmaxf(pred, 1.175494351e-38f)) : -100.0f;
                    float lgn = (om   > 0.0f) ? __logf(fmaxf(om,   1.175494351e-38f)) : -100.0f;
                    acc += (double)lgp * (double)np + (double)lgn * (double)(8 - np);
                }
            }
        }
        #pragma unroll
        for (int off = 32; off; off >>= 1) acc += __shfl_xor(acc, off);
        if (lane == 0) wsum[wid] = acc;
        __syncthreads();
        if (tid == 0) {
            double s = 0.0;
            #pragma unroll
            for (int w = 0; w < 7; ++w) s += wsum[w];
            atomicAdd(&g_accbc[bc].v, -s * (1.0 / (448.0 * 448.0)));   // own line per bc
            asm volatile("s_waitcnt vmcnt(0)" ::: "memory");            // add performed
        }
    }
    // ---- spread fenceless completion (proven R7 protocol, 14 arrivals/bc) ----
    if (tid == 0) {
        sh_last = 0;
        int t = __hip_atomic_fetch_add(&g_tdone[bc].v, 1, __ATOMIC_RELAXED, __HIP_MEMORY_SCOPE_AGENT);
        if (t == NT2 - 1) {
            atomicExch(&g_tdone[bc].v, 0);
            asm volatile("s_waitcnt vmcnt(0)" ::: "memory");
            int d = __hip_atomic_fetch_add(&g_bdone, 1, __ATOMIC_RELAXED, __HIP_MEMORY_SCOPE_AGENT);
            if (d == TOTBC - 1) {
                atomicExch(&g_bdone, 0);
                sh_last = 1;
            }
        }
    }
    __syncthreads();
    if (sh_last) {
        if (tid == 0) sh_sa = 0;
        __syncthreads();
        double s = 0.0;
        if (tid < TOTBC) {
            ull bits = atomicExch((ull*)&g_accbc[tid].v, 0ULL);   // read+reset at MALL
            s = __longlong_as_double(bits);
            if (label[tid] != 0) atomicAdd(&sh_sa, 1);
        }
        #pragma unroll
        for (int off = 32; off; off >>= 1) s += __shfl_xor(s, off);
        if (lane == 0) wsum[wid] = s;
        __syncthreads();
        if (tid == 0) {
            double tot = 0.0;
            #pragma unroll
            for (int w = 0; w < 7; ++w) tot += wsum[w];
            out[0] = (float)(tot / (double)sh_sa);
        }
    }
}

extern "C" void kernel_launch(void* const* d_in, const int* in_sizes, int n_in,
                              void* d_out, int out_size, void* d_ws, size_t ws_size,
                              hipStream_t stream) {
    const float* smap  = (const float*)d_in[0];   // (L,B,N,784)
    const float* score = (const float*)d_in[1];   // (B,N,C)
    const int*   label = (const int*)d_in[2];     // (B,C)
    const int*   gt    = (const int*)d_in[3];     // (B,448,448)
    float* out = (float*)d_out;

    hipLaunchKernelGGL(k_rm,  dim3(RM_UNITS + CVT_BLKS), dim3(256), 0, stream, smap, gt);
    hipLaunchKernelGGL(k_adj, dim3(BNUM * NNUM),         dim3(320), 0, stream);
    hipLaunchKernelGGL(k_cm,  dim3(TOTBC),               dim3(320), 0, stream, score, label);
    hipLaunchKernelGGL(k_bce, dim3(BCEBLK),              dim3(448), 0, stream, label, out);
}

// Round 12
// 55.628 us; speedup vs baseline: 1.4948x; 1.0265x over previous
//
#include <hip/hip_runtime.h>
#include <math.h>

#define LNUM 6
#define BNUM 8
#define NNUM 300
#define CNUM 20
#define HW   784
#define HW4  196   // HW/4
#define GH   448
#define NW   16    // mask words per (b,n): permuted bit order (popcount-invariant)
#define AW   5     // adjacency row words (300 bits -> 5 x u64)
#define RT   16    // bce rows per tile
#define NTILE 28   // 448/16 tiles per (b,c)
#define TOTBC  (BNUM*CNUM)          // 160
#define TOTBLK (TOTBC*NTILE)        // 4480
#define GT4    (BNUM*GH*GH/4)       // 401408 int4-groups of gt

typedef unsigned long long ull;

// ---- device scratch (every consumed entry rewritten each launch; counters/acc self-reset) ----
__device__ float         g_rm [BNUM*NNUM*HW];
__device__ ull           g_T  [BNUM*NNUM*NW];
__device__ int           g_s  [BNUM*NNUM];
__device__ ull           g_adj[BNUM*NNUM*AW];
__device__ float         g_mm [TOTBC*HW];
__device__ unsigned char g_gt8[BNUM*GH*GH];   // gt as u8 (values 0..20), small + cacheable
// one 128-B cacheline per entry -> no cross-entry atomic serialization
struct PadD { double v; double pad[15]; };
struct PadI { int v;    int    pad[31]; };
__device__ PadD g_accbc[TOTBC];   // f64 partial per bc; exchanged to 0 by final block
__device__ PadI g_tdone[TOTBC];   // tile-done per bc (28 arrivals); reset by bc-last
__device__ int  g_bdone = 0;      // root line (160 arrivals); reset by final block

// One block per (b,n): mean over L (float4), relu, max-normalize, rm + bitmask + popcount.
// Additionally each thread with global id < GT4 converts one int4 of gt -> 4 u8 (distributed,
// no tail blocks).
__global__ void k_rm(const float* __restrict__ sm, const int* __restrict__ gt) {
    int bn  = blockIdx.x;
    int tid = threadIdx.x;               // 256
    int lane = tid & 63, wid = tid >> 6;
    // ---- distributed gt -> u8 (independent of everything below) ----
    {
        int gidx = bn * 256 + tid;       // 2400*256 = 614400 >= GT4
        if (gidx < GT4) {
            int4 v = ((const int4*)gt)[gidx];
            unsigned w = (unsigned)(v.x & 255) | ((unsigned)(v.y & 255) << 8) |
                         ((unsigned)(v.z & 255) << 16) | ((unsigned)(v.w & 255) << 24);
            ((unsigned*)g_gt8)[gidx] = w;
        }
    }
    __shared__ float wmax[4];
    __shared__ int   scount;
    if (tid == 0) scount = 0;
    const size_t lstr4 = (size_t)BNUM * NNUM * HW4;
    const float4* base = (const float4*)sm + (size_t)bn * HW4;
    bool act = tid < HW4;
    float4 v = {0.f, 0.f, 0.f, 0.f};
    if (act) {
        float4 a = {0.f, 0.f, 0.f, 0.f};
        #pragma unroll
        for (int l = 0; l < LNUM; ++l) {
            float4 x = base[(size_t)l * lstr4 + tid];
            a.x += x.x; a.y += x.y; a.z += x.z; a.w += x.w;
        }
        v.x = fmaxf(__fdiv_rn(a.x, 6.0f), 0.0f);
        v.y = fmaxf(__fdiv_rn(a.y, 6.0f), 0.0f);
        v.z = fmaxf(__fdiv_rn(a.z, 6.0f), 0.0f);
        v.w = fmaxf(__fdiv_rn(a.w, 6.0f), 0.0f);
    }
    float lm = fmaxf(fmaxf(v.x, v.y), fmaxf(v.z, v.w));
    #pragma unroll
    for (int off = 32; off; off >>= 1) lm = fmaxf(lm, __shfl_xor(lm, off));
    if (lane == 0) wmax[wid] = lm;
    __syncthreads();
    float mx = fmaxf(fmaxf(wmax[0], wmax[1]), fmaxf(wmax[2], wmax[3]));
    float d = mx + 1e-6f;
    float4 nv;
    nv.x = __fdiv_rn(v.x, d); nv.y = __fdiv_rn(v.y, d);
    nv.z = __fdiv_rn(v.z, d); nv.w = __fdiv_rn(v.w, d);
    if (act) ((float4*)g_rm)[(size_t)bn * HW4 + tid] = nv;
    float c[4] = {nv.x, nv.y, nv.z, nv.w};
    #pragma unroll
    for (int k = 0; k < 4; ++k) {
        bool pr = act && (c[k] > 0.7f);
        ull ball = __ballot(pr);
        if (lane == 0) {
            g_T[(size_t)bn * NW + k * 4 + wid] = ball;
            atomicAdd(&scount, __popcll(ball));
        }
    }
    __syncthreads();
    if (tid == 0) g_s[bn] = scount;
}

// One block per (b,i): adjacency row i via popcount(AND) + exact f32 (iou+dice)/2 > 0.5
__global__ void k_adj() {
    int blk = blockIdx.x;                // b*300 + i
    int b = blk / NNUM;
    int tid = threadIdx.x;               // 320 (5 waves)
    __shared__ ull Ti[NW];
    __shared__ int si_sh;
    if (tid < NW)  Ti[tid] = g_T[(size_t)blk * NW + tid];
    if (tid == NW) si_sh = g_s[blk];
    __syncthreads();
    bool a = false;
    int j = tid;
    if (j < NNUM) {
        const ull* Tj = &g_T[((size_t)b * NNUM + j) * NW];
        int inter = 0;
        #pragma unroll
        for (int w = 0; w < NW; ++w) inter += __popcll(Ti[w] & Tj[w]);
        int si = si_sh, sj = g_s[b * NNUM + j];
        int uni = si + sj - inter, tot = si + sj;
        float iou  = (uni == 0) ? 1.0f : __fdiv_rn((float)inter, (float)uni);
        float dice = (tot == 0) ? 1.0f : __fdiv_rn(2.0f * (float)inter, (float)tot);
        a = (0.5f * (iou + dice)) > 0.5f;
    }
    ull ball = __ballot(a);
    if ((tid & 63) == 0) g_adj[(size_t)blk * AW + (tid >> 6)] = ball;
}

// One block per active (b,c), 320 threads: FULLY PARALLEL cluster fixed point + float4 meanmap.
__global__ void __launch_bounds__(320)
k_cm(const float* __restrict__ score, const int* __restrict__ label) {
    int blk = blockIdx.x;                // b*C + c
    if (label[blk] == 0) return;         // block-uniform, before any barrier
    int b = blk / CNUM, c = blk - b * CNUM;
    int tid = threadIdx.x;               // 320 (5 waves)
    int lane = tid & 63, wid = tid >> 6;
    __shared__ ull adj_sh[NNUM][AW];
    __shared__ ull cand[AW], fin[AW], nwv[AW];
    __shared__ float wbv[AW], wbva[AW];
    __shared__ int   wbi[AW], wbia[AW];
    __shared__ int sh_has, sh_go;
    __shared__ float sh_cf;
    for (int idx = tid; idx < NNUM * AW; idx += 320)
        ((ull*)adj_sh)[idx] = g_adj[(size_t)b * NNUM * AW + idx];
    int j = tid;
    bool cb = false;
    float sc = -INFINITY;
    if (j < NNUM) {
        sc = score[((size_t)b * NNUM + j) * CNUM + c];
        cb = sc > 0.01f;
    }
    ull ball = __ballot(cb);
    if (lane == 0) cand[wid] = ball;
    float bv  = cb ? sc : -INFINITY;          int bi  = cb ? j : NNUM;
    float bva = (j < NNUM) ? sc : -INFINITY;  int bia = (j < NNUM) ? j : NNUM;
    #pragma unroll
    for (int off = 1; off < 64; off <<= 1) {
        float ov = __shfl_xor(bv, off);  int oi = __shfl_xor(bi, off);
        if (ov > bv || (ov == bv && oi < bi)) { bv = ov; bi = oi; }
        float ova = __shfl_xor(bva, off); int oia = __shfl_xor(bia, off);
        if (ova > bva || (ova == bva && oia < bia)) { bva = ova; bia = oia; }
    }
    if (lane == 0) { wbv[wid] = bv; wbi[wid] = bi; wbva[wid] = bva; wbia[wid] = bia; }
    __syncthreads();
    if (tid == 0) {
        float cv = -INFINITY; int ci = NNUM;
        float cva = -INFINITY; int cia = NNUM;
        #pragma unroll
        for (int w = 0; w < AW; ++w) {
            if (wbv[w] > cv)   { cv = wbv[w];   ci = wbi[w]; }
            if (wbva[w] > cva) { cva = wbva[w]; cia = wbia[w]; }
        }
        bool has = (cand[0] | cand[1] | cand[2] | cand[3] | cand[4]) != 0ULL;
        sh_has = has ? 1 : 0;
        if (has) {
            #pragma unroll
            for (int w = 0; w < AW; ++w) fin[w] = cand[w] & adj_sh[ci][w];
        } else {
            #pragma unroll
            for (int w = 0; w < AW; ++w)
                fin[w] = ((cia >> 6) == w) ? (1ULL << (cia & 63)) : 0ULL;
        }
    }
    __syncthreads();
    if (sh_has) {
        for (int it = 0; it < NNUM + 2; ++it) {
            bool nb = false;
            if (j < NNUM && cb) {
                ull o = (adj_sh[j][0] & fin[0]) | (adj_sh[j][1] & fin[1]) |
                        (adj_sh[j][2] & fin[2]) | (adj_sh[j][3] & fin[3]) |
                        (adj_sh[j][4] & fin[4]);
                nb = (o != 0ULL);         // adj symmetric: row j == column j
            }
            ull nball = __ballot(nb);
            if (lane == 0) nwv[wid] = nball;
            __syncthreads();
            if (wid == 0) {
                bool ch = (lane < AW) && (nwv[lane] != fin[lane]);
                ull chb = __ballot(ch);
                if (lane == 0) sh_go = (chb != 0ULL) ? 1 : 0;
                if (lane < AW) fin[lane] = nwv[lane];
            }
            __syncthreads();
            if (!sh_go) break;            // sh_go rewritten only after next barrier
        }
    }
    if (tid == 0) {
        int cs = 0;
        for (int w = 0; w < AW; ++w) cs += __popcll(fin[w]);
        sh_cf = (float)cs;
    }
    __syncthreads();
    if (tid < HW4) {
        float4 a = {0.f, 0.f, 0.f, 0.f};
        for (int w = 0; w < AW; ++w) {
            ull word = fin[w];
            while (word) {
                int jj = w * 64 + (__ffsll(word) - 1);
                word &= word - 1;
                float4 r = ((const float4*)g_rm)[((size_t)b * NNUM + jj) * HW4 + tid];
                a.x += r.x; a.y += r.y; a.z += r.z; a.w += r.w;
            }
        }
        float cdiv = sh_cf;
        float4 o;
        o.x = __fdiv_rn(a.x, cdiv); o.y = __fdiv_rn(a.y, cdiv);
        o.z = __fdiv_rn(a.z, cdiv); o.w = __fdiv_rn(a.w, cdiv);
        ((float4*)g_mm)[(size_t)blk * HW4 + tid] = o;
    }
}

// One block per (bc, tile), 448 threads: R7 structure, u8 gt reads (16B/thread).
// Fenceless spread finalization (28 -> 160 arrivals), all self-resetting.
__global__ void __launch_bounds__(448)
k_bce(const int* __restrict__ label, float* __restrict__ out) {
    int blk = blockIdx.x;                // bc*NTILE + tile
    int bc = blk / NTILE, tile = blk - bc * NTILE;
    int tid = threadIdx.x;               // 448 (7 waves)
    int lane = tid & 63, wid = tid >> 6;
    __shared__ float m[HW];
    __shared__ float rowY[RT * 28];
    __shared__ double wsum[7];
    __shared__ int sh_last, sh_sa;
    bool active = (label[bc] != 0);      // block-uniform
    if (active) {
        int b = bc / CNUM, c = bc - b * CNUM;
        if (tid < HW4) ((float4*)m)[tid] = ((const float4*)g_mm)[(size_t)bc * HW4 + tid];
        __syncthreads();
        int row0 = tile * RT;
        {
            int r = tid / 28, x = tid - (tid / 28) * 28;
            int oy = row0 + r;
            float iy = fmaf((float)oy, 0.0625f, -0.46875f);   // (oy+0.5)/16-0.5, exact
            float y0f = floorf(iy);
            float wy = iy - y0f;
            int y0 = (int)y0f;
            if (y0 < 0) { y0 = 0; wy = 0.0f; } else if (y0 > 26) { y0 = 26; wy = 1.0f; }
            float lo = m[y0 * 28 + x], hi = m[y0 * 28 + 28 + x];
            rowY[tid] = lo + wy * (hi - lo);
        }
        __syncthreads();
        double acc = 0.0;
        {
            int r = tid / 28, jx = tid - (tid / 28) * 28;
            const unsigned char* g8 = g_gt8 + ((size_t)b * GH + row0 + r) * GH;
            int cp1 = c + 1;
            if (jx < 27) {
                float rY0 = rowY[tid], rY1 = rowY[tid + 1];
                float sl = rY1 - rY0;
                ull w0 = *(const ull*)(g8 + 16 * jx + 8);    // 8-aligned
                ull w1 = *(const ull*)(g8 + 16 * jx + 16);
                #pragma unroll
                for (int k = 0; k < 16; ++k) {
                    int gv = (int)((k < 8 ? (w0 >> (8 * k)) : (w1 >> (8 * (k - 8)))) & 255);
                    float wk = fmaf((float)k, 0.0625f, 0.03125f);   // (2k+1)/32, exact
                    float pred = rY0 + wk * sl;
                    float xv = (gv == cp1) ? pred : 1.0f - pred;
                    float lg = __logf(fmaxf(xv, 1.175494351e-38f));
                    acc += (double)((xv > 0.0f) ? lg : -100.0f);
                }
            } else {
                #pragma unroll
                for (int side = 0; side < 2; ++side) {
                    float pred = rowY[r * 28 + (side ? 27 : 0)];
                    ull w = *(const ull*)(g8 + (side ? 440 : 0));
                    int np = 0;
                    #pragma unroll
                    for (int uu = 0; uu < 8; ++uu)
                        np += (((w >> (8 * uu)) & 255) == (unsigned)cp1);
                    float om = 1.0f - pred;
                    float lgp = (pred > 0.0f) ? __logf(fmaxf(pred, 1.175494351e-38f)) : -100.0f;
                    float lgn = (om   > 0.0f) ? __logf(fmaxf(om,   1.175494351e-38f)) : -100.0f;
                    acc += (double)lgp * (double)np + (double)lgn * (double)(8 - np);
                }
            }
        }
        #pragma unroll
        for (int off = 32; off; off >>= 1) acc += __shfl_xor(acc, off);
        if (lane == 0) wsum[wid] = acc;
        __syncthreads();
        if (tid == 0) {
            double s = 0.0;
            #pragma unroll
            for (int w = 0; w < 7; ++w) s += wsum[w];
            atomicAdd(&g_accbc[bc].v, -s * (1.0 / (448.0 * 448.0)));   // own line per bc
            asm volatile("s_waitcnt vmcnt(0)" ::: "memory");            // add performed
        }
    }
    // ---- spread fenceless completion (proven R7 protocol) ----
    if (tid == 0) {
        sh_last = 0;
        int t = __hip_atomic_fetch_add(&g_tdone[bc].v, 1, __ATOMIC_RELAXED, __HIP_MEMORY_SCOPE_AGENT);
        if (t == NTILE - 1) {            // 28th arrival of this bc
            atomicExch(&g_tdone[bc].v, 0);
            asm volatile("s_waitcnt vmcnt(0)" ::: "memory");
            int d = __hip_atomic_fetch_add(&g_bdone, 1, __ATOMIC_RELAXED, __HIP_MEMORY_SCOPE_AGENT);
            if (d == TOTBC - 1) {
                atomicExch(&g_bdone, 0);
                sh_last = 1;
            }
        }
    }
    __syncthreads();
    if (sh_last) {
        if (tid == 0) sh_sa = 0;
        __syncthreads();
        double s = 0.0;
        if (tid < TOTBC) {
            ull bits = atomicExch((ull*)&g_accbc[tid].v, 0ULL);   // read+reset at MALL
            s = __longlong_as_double(bits);
            if (label[tid] != 0) atomicAdd(&sh_sa, 1);
        }
        #pragma unroll
        for (int off = 32; off; off >>= 1) s += __shfl_xor(s, off);
        if (lane == 0) wsum[wid] = s;
        __syncthreads();
        if (tid == 0) {
            double tot = 0.0;
            #pragma unroll
            for (int w = 0; w < 7; ++w) tot += wsum[w];
            out[0] = (float)(tot / (double)sh_sa);
        }
    }
}

extern "C" void kernel_launch(void* const* d_in, const int* in_sizes, int n_in,
                              void* d_out, int out_size, void* d_ws, size_t ws_size,
                              hipStream_t stream) {
    const float* smap  = (const float*)d_in[0];   // (L,B,N,784)
    const float* score = (const float*)d_in[1];   // (B,N,C)
    const int*   label = (const int*)d_in[2];     // (B,C)
    const int*   gt    = (const int*)d_in[3];     // (B,448,448)
    float* out = (float*)d_out;

    hipLaunchKernelGGL(k_rm,  dim3(BNUM * NNUM), dim3(256), 0, stream, smap, gt);
    hipLaunchKernelGGL(k_adj, dim3(BNUM * NNUM), dim3(320), 0, stream);
    hipLaunchKernelGGL(k_cm,  dim3(TOTBC),       dim3(320), 0, stream, score, label);
    hipLaunchKernelGGL(k_bce, dim3(TOTBLK),      dim3(448), 0, stream, label, out);
}

// Round 13
// 54.197 us; speedup vs baseline: 1.5343x; 1.0264x over previous
//
#include <hip/hip_runtime.h>
#include <math.h>

#define LNUM 6
#define BNUM 8
#define NNUM 300
#define CNUM 20
#define HW   784
#define HW4  196   // HW/4
#define GH   448
#define NW   16    // mask words per (b,n): permuted bit order (popcount-invariant)
#define AW   5     // adjacency row words (300 bits -> 5 x u64)
#define RT   16    // bce rows per tile
#define NTILE 28   // 448/16 tiles per (b,c)
#define TOTBC  (BNUM*CNUM)          // 160
#define TOTBLK (TOTBC*NTILE)        // 4480
#define GT4    (BNUM*GH*GH/4)       // 401408 int4-groups of gt

typedef unsigned long long ull;

// ---- device scratch (every consumed entry rewritten each launch; counters/acc self-reset) ----
__device__ float         g_rm [BNUM*NNUM*HW];
__device__ ull           g_T  [BNUM*NNUM*NW];
__device__ int           g_s  [BNUM*NNUM];
__device__ ull           g_adj[BNUM*NNUM*AW];
__device__ float         g_mm [TOTBC*HW];
__device__ unsigned char g_gt8[BNUM*GH*GH];   // gt as u8 (values 0..20), small + cacheable
// one 128-B cacheline per entry -> no cross-entry atomic serialization
struct PadD { double v; double pad[15]; };
struct PadI { int v;    int    pad[31]; };
__device__ PadD g_accbc[TOTBC];   // f64 partial per bc; exchanged to 0 by final block
__device__ PadI g_tdone[TOTBC];   // tile-done per bc (28 arrivals); reset by bc-last
__device__ int  g_bdone = 0;      // root line (160 arrivals); reset by final block

// One block per (b,n): mean over L (float4), relu, max-normalize, rm + bitmask + popcount.
// Additionally each thread with global id < GT4 converts one int4 of gt -> 4 u8 (distributed).
__global__ void k_rm(const float* __restrict__ sm, const int* __restrict__ gt) {
    int bn  = blockIdx.x;
    int tid = threadIdx.x;               // 256
    int lane = tid & 63, wid = tid >> 6;
    {
        int gidx = bn * 256 + tid;       // 2400*256 = 614400 >= GT4
        if (gidx < GT4) {
            int4 v = ((const int4*)gt)[gidx];
            unsigned w = (unsigned)(v.x & 255) | ((unsigned)(v.y & 255) << 8) |
                         ((unsigned)(v.z & 255) << 16) | ((unsigned)(v.w & 255) << 24);
            ((unsigned*)g_gt8)[gidx] = w;
        }
    }
    __shared__ float wmax[4];
    __shared__ int   scount;
    if (tid == 0) scount = 0;
    const size_t lstr4 = (size_t)BNUM * NNUM * HW4;
    const float4* base = (const float4*)sm + (size_t)bn * HW4;
    bool act = tid < HW4;
    float4 v = {0.f, 0.f, 0.f, 0.f};
    if (act) {
        float4 a = {0.f, 0.f, 0.f, 0.f};
        #pragma unroll
        for (int l = 0; l < LNUM; ++l) {
            float4 x = base[(size_t)l * lstr4 + tid];
            a.x += x.x; a.y += x.y; a.z += x.z; a.w += x.w;
        }
        v.x = fmaxf(__fdiv_rn(a.x, 6.0f), 0.0f);
        v.y = fmaxf(__fdiv_rn(a.y, 6.0f), 0.0f);
        v.z = fmaxf(__fdiv_rn(a.z, 6.0f), 0.0f);
        v.w = fmaxf(__fdiv_rn(a.w, 6.0f), 0.0f);
    }
    float lm = fmaxf(fmaxf(v.x, v.y), fmaxf(v.z, v.w));
    #pragma unroll
    for (int off = 32; off; off >>= 1) lm = fmaxf(lm, __shfl_xor(lm, off));
    if (lane == 0) wmax[wid] = lm;
    __syncthreads();
    float mx = fmaxf(fmaxf(wmax[0], wmax[1]), fmaxf(wmax[2], wmax[3]));
    float d = mx + 1e-6f;
    float4 nv;
    nv.x = __fdiv_rn(v.x, d); nv.y = __fdiv_rn(v.y, d);
    nv.z = __fdiv_rn(v.z, d); nv.w = __fdiv_rn(v.w, d);
    if (act) ((float4*)g_rm)[(size_t)bn * HW4 + tid] = nv;
    float c[4] = {nv.x, nv.y, nv.z, nv.w};
    #pragma unroll
    for (int k = 0; k < 4; ++k) {
        bool pr = act && (c[k] > 0.7f);
        ull ball = __ballot(pr);
        if (lane == 0) {
            g_T[(size_t)bn * NW + k * 4 + wid] = ball;
            atomicAdd(&scount, __popcll(ball));
        }
    }
    __syncthreads();
    if (tid == 0) g_s[bn] = scount;
}

// One block per (b,i): adjacency row i via popcount(AND) + exact f32 (iou+dice)/2 > 0.5
__global__ void k_adj() {
    int blk = blockIdx.x;                // b*300 + i
    int b = blk / NNUM;
    int tid = threadIdx.x;               // 320 (5 waves)
    __shared__ ull Ti[NW];
    __shared__ int si_sh;
    if (tid < NW)  Ti[tid] = g_T[(size_t)blk * NW + tid];
    if (tid == NW) si_sh = g_s[blk];
    __syncthreads();
    bool a = false;
    int j = tid;
    if (j < NNUM) {
        const ull* Tj = &g_T[((size_t)b * NNUM + j) * NW];
        int inter = 0;
        #pragma unroll
        for (int w = 0; w < NW; ++w) inter += __popcll(Ti[w] & Tj[w]);
        int si = si_sh, sj = g_s[b * NNUM + j];
        int uni = si + sj - inter, tot = si + sj;
        float iou  = (uni == 0) ? 1.0f : __fdiv_rn((float)inter, (float)uni);
        float dice = (tot == 0) ? 1.0f : __fdiv_rn(2.0f * (float)inter, (float)tot);
        a = (0.5f * (iou + dice)) > 0.5f;
    }
    ull ball = __ballot(a);
    if ((tid & 63) == 0) g_adj[(size_t)blk * AW + (tid >> 6)] = ball;
}

// One block per active (b,c), 320 threads: FULLY PARALLEL cluster fixed point + float4 meanmap.
__global__ void __launch_bounds__(320)
k_cm(const float* __restrict__ score, const int* __restrict__ label) {
    int blk = blockIdx.x;                // b*C + c
    if (label[blk] == 0) return;         // block-uniform, before any barrier
    int b = blk / CNUM, c = blk - b * CNUM;
    int tid = threadIdx.x;               // 320 (5 waves)
    int lane = tid & 63, wid = tid >> 6;
    __shared__ ull adj_sh[NNUM][AW];
    __shared__ ull cand[AW], fin[AW], nwv[AW];
    __shared__ float wbv[AW], wbva[AW];
    __shared__ int   wbi[AW], wbia[AW];
    __shared__ int sh_has, sh_go;
    __shared__ float sh_cf;
    for (int idx = tid; idx < NNUM * AW; idx += 320)
        ((ull*)adj_sh)[idx] = g_adj[(size_t)b * NNUM * AW + idx];
    int j = tid;
    bool cb = false;
    float sc = -INFINITY;
    if (j < NNUM) {
        sc = score[((size_t)b * NNUM + j) * CNUM + c];
        cb = sc > 0.01f;
    }
    ull ball = __ballot(cb);
    if (lane == 0) cand[wid] = ball;
    float bv  = cb ? sc : -INFINITY;          int bi  = cb ? j : NNUM;
    float bva = (j < NNUM) ? sc : -INFINITY;  int bia = (j < NNUM) ? j : NNUM;
    #pragma unroll
    for (int off = 1; off < 64; off <<= 1) {
        float ov = __shfl_xor(bv, off);  int oi = __shfl_xor(bi, off);
        if (ov > bv || (ov == bv && oi < bi)) { bv = ov; bi = oi; }
        float ova = __shfl_xor(bva, off); int oia = __shfl_xor(bia, off);
        if (ova > bva || (ova == bva && oia < bia)) { bva = ova; bia = oia; }
    }
    if (lane == 0) { wbv[wid] = bv; wbi[wid] = bi; wbva[wid] = bva; wbia[wid] = bia; }
    __syncthreads();
    if (tid == 0) {
        float cv = -INFINITY; int ci = NNUM;
        float cva = -INFINITY; int cia = NNUM;
        #pragma unroll
        for (int w = 0; w < AW; ++w) {
            if (wbv[w] > cv)   { cv = wbv[w];   ci = wbi[w]; }
            if (wbva[w] > cva) { cva = wbva[w]; cia = wbia[w]; }
        }
        bool has = (cand[0] | cand[1] | cand[2] | cand[3] | cand[4]) != 0ULL;
        sh_has = has ? 1 : 0;
        if (has) {
            #pragma unroll
            for (int w = 0; w < AW; ++w) fin[w] = cand[w] & adj_sh[ci][w];
        } else {
            #pragma unroll
            for (int w = 0; w < AW; ++w)
                fin[w] = ((cia >> 6) == w) ? (1ULL << (cia & 63)) : 0ULL;
        }
    }
    __syncthreads();
    if (sh_has) {
        for (int it = 0; it < NNUM + 2; ++it) {
            bool nb = false;
            if (j < NNUM && cb) {
                ull o = (adj_sh[j][0] & fin[0]) | (adj_sh[j][1] & fin[1]) |
                        (adj_sh[j][2] & fin[2]) | (adj_sh[j][3] & fin[3]) |
                        (adj_sh[j][4] & fin[4]);
                nb = (o != 0ULL);         // adj symmetric: row j == column j
            }
            ull nball = __ballot(nb);
            if (lane == 0) nwv[wid] = nball;
            __syncthreads();
            if (wid == 0) {
                bool ch = (lane < AW) && (nwv[lane] != fin[lane]);
                ull chb = __ballot(ch);
                if (lane == 0) sh_go = (chb != 0ULL) ? 1 : 0;
                if (lane < AW) fin[lane] = nwv[lane];
            }
            __syncthreads();
            if (!sh_go) break;            // sh_go rewritten only after next barrier
        }
    }
    if (tid == 0) {
        int cs = 0;
        for (int w = 0; w < AW; ++w) cs += __popcll(fin[w]);
        sh_cf = (float)cs;
    }
    __syncthreads();
    if (tid < HW4) {
        float4 a = {0.f, 0.f, 0.f, 0.f};
        for (int w = 0; w < AW; ++w) {
            ull word = fin[w];
            while (word) {
                int jj = w * 64 + (__ffsll(word) - 1);
                word &= word - 1;
                float4 r = ((const float4*)g_rm)[((size_t)b * NNUM + jj) * HW4 + tid];
                a.x += r.x; a.y += r.y; a.z += r.z; a.w += r.w;
            }
        }
        float cdiv = sh_cf;
        float4 o;
        o.x = __fdiv_rn(a.x, cdiv); o.y = __fdiv_rn(a.y, cdiv);
        o.z = __fdiv_rn(a.z, cdiv); o.w = __fdiv_rn(a.w, cdiv);
        ((float4*)g_mm)[(size_t)blk * HW4 + tid] = o;
    }
}

// One block per (bc, tile), 448 threads: BARRIER-FREE main path. Each thread derives
// rY0/rY1 directly from L2-hot g_mm (same expression tree as the LDS version ->
// bit-identical), reads u8 gt, accumulates 16 BCE terms in f32, converts to f64 once.
// One barrier total (before wsum reduce). Fenceless spread finalization.
__global__ void __launch_bounds__(448)
k_bce(const int* __restrict__ label, float* __restrict__ out) {
    int blk = blockIdx.x;                // bc*NTILE + tile
    int bc = blk / NTILE, tile = blk - bc * NTILE;
    int tid = threadIdx.x;               // 448 (7 waves)
    int lane = tid & 63, wid = tid >> 6;
    __shared__ double wsum[7];
    __shared__ int sh_last, sh_sa;
    bool active = (label[bc] != 0);      // block-uniform
    double acc = 0.0;
    if (active) {
        int b = bc / CNUM, c = bc - b * CNUM;
        int row0 = tile * RT;
        int r = tid / 28, jx = tid - (tid / 28) * 28;
        int oy = row0 + r;
        float iy = fmaf((float)oy, 0.0625f, -0.46875f);   // (oy+0.5)/16-0.5, exact
        float y0f = floorf(iy);
        float wy = iy - y0f;
        int y0 = (int)y0f;
        if (y0 < 0) { y0 = 0; wy = 0.0f; } else if (y0 > 26) { y0 = 26; wy = 1.0f; }
        const float* mrow = g_mm + (size_t)bc * HW + y0 * 28;
        const unsigned char* g8 = g_gt8 + ((size_t)b * GH + oy) * GH;
        int cp1 = c + 1;
        float facc = 0.0f;
        if (jx < 27) {
            float lo0 = mrow[jx],     hi0 = mrow[28 + jx];
            float lo1 = mrow[jx + 1], hi1 = mrow[29 + jx];
            float rY0 = lo0 + wy * (hi0 - lo0);           // identical exprs to LDS version
            float rY1 = lo1 + wy * (hi1 - lo1);
            float sl = rY1 - rY0;
            ull w0 = *(const ull*)(g8 + 16 * jx + 8);     // 8-aligned
            ull w1 = *(const ull*)(g8 + 16 * jx + 16);
            #pragma unroll
            for (int k = 0; k < 16; ++k) {
                int gv = (int)((k < 8 ? (w0 >> (8 * k)) : (w1 >> (8 * (k - 8)))) & 255);
                float wk = fmaf((float)k, 0.0625f, 0.03125f);   // (2k+1)/32, exact
                float pred = rY0 + wk * sl;
                float xv = (gv == cp1) ? pred : 1.0f - pred;
                float lg = __logf(fmaxf(xv, 1.175494351e-38f));
                facc += (xv > 0.0f) ? lg : -100.0f;
            }
        } else {
            float loL = mrow[0],  hiL = mrow[28];
            float loR = mrow[27], hiR = mrow[55];
            float predL = loL + wy * (hiL - loL);
            float predR = loR + wy * (hiR - loR);
            #pragma unroll
            for (int side = 0; side < 2; ++side) {
                float pred = side ? predR : predL;
                ull w = *(const ull*)(g8 + (side ? 440 : 0));
                int np = 0;
                #pragma unroll
                for (int uu = 0; uu < 8; ++uu)
                    np += (((w >> (8 * uu)) & 255) == (unsigned)cp1);
                float om = 1.0f - pred;
                float lgp = (pred > 0.0f) ? __logf(fmaxf(pred, 1.175494351e-38f)) : -100.0f;
                float lgn = (om   > 0.0f) ? __logf(fmaxf(om,   1.175494351e-38f)) : -100.0f;
                facc += lgp * (float)np + lgn * (float)(8 - np);
            }
        }
        acc = (double)facc;
        #pragma unroll
        for (int off = 32; off; off >>= 1) acc += __shfl_xor(acc, off);
        if (lane == 0) wsum[wid] = acc;
    }
    __syncthreads();                      // single barrier (also covers wsum for tid 0)
    if (tid == 0) {
        sh_last = 0;
        if (active) {
            double s = 0.0;
            #pragma unroll
            for (int w = 0; w < 7; ++w) s += wsum[w];
            atomicAdd(&g_accbc[bc].v, -s * (1.0 / (448.0 * 448.0)));   // own line per bc
            asm volatile("s_waitcnt vmcnt(0)" ::: "memory");            // add performed
        }
        int t = __hip_atomic_fetch_add(&g_tdone[bc].v, 1, __ATOMIC_RELAXED, __HIP_MEMORY_SCOPE_AGENT);
        if (t == NTILE - 1) {            // 28th arrival of this bc
            atomicExch(&g_tdone[bc].v, 0);
            asm volatile("s_waitcnt vmcnt(0)" ::: "memory");
            int d = __hip_atomic_fetch_add(&g_bdone, 1, __ATOMIC_RELAXED, __HIP_MEMORY_SCOPE_AGENT);
            if (d == TOTBC - 1) {
                atomicExch(&g_bdone, 0);
                sh_last = 1;
            }
        }
    }
    __syncthreads();
    if (sh_last) {
        if (tid == 0) sh_sa = 0;
        __syncthreads();
        double s = 0.0;
        if (tid < TOTBC) {
            ull bits = atomicExch((ull*)&g_accbc[tid].v, 0ULL);   // read+reset at MALL
            s = __longlong_as_double(bits);
            if (label[tid] != 0) atomicAdd(&sh_sa, 1);
        }
        #pragma unroll
        for (int off = 32; off; off >>= 1) s += __shfl_xor(s, off);
        if (lane == 0) wsum[wid] = s;
        __syncthreads();
        if (tid == 0) {
            double tot = 0.0;
            #pragma unroll
            for (int w = 0; w < 7; ++w) tot += wsum[w];
            out[0] = (float)(tot / (double)sh_sa);
        }
    }
}

extern "C" void kernel_launch(void* const* d_in, const int* in_sizes, int n_in,
                              void* d_out, int out_size, void* d_ws, size_t ws_size,
                              hipStream_t stream) {
    const float* smap  = (const float*)d_in[0];   // (L,B,N,784)
    const float* score = (const float*)d_in[1];   // (B,N,C)
    const int*   label = (const int*)d_in[2];     // (B,C)
    const int*   gt    = (const int*)d_in[3];     // (B,448,448)
    float* out = (float*)d_out;

    hipLaunchKernelGGL(k_rm,  dim3(BNUM * NNUM), dim3(256), 0, stream, smap, gt);
    hipLaunchKernelGGL(k_adj, dim3(BNUM * NNUM), dim3(320), 0, stream);
    hipLaunchKernelGGL(k_cm,  dim3(TOTBC),       dim3(320), 0, stream, score, label);
    hipLaunchKernelGGL(k_bce, dim3(TOTBLK),      dim3(448), 0, stream, label, out);
}